// Round 1
// baseline (3420.909 us; speedup 1.0000x reference)
//
#include <hip/hip_runtime.h>
#include <hip/hip_bf16.h>

#define T_SEQ 2048
#define H_CNT 16
#define B_SZ  2

// ---------------------------------------------------------------------------
// Tiled fp32 GEMM: C[M,N] = A[M,K] @ B[K,N] (+ bias).  BM=BN=128, BK=8,
// 256 threads, 8x8 micro-tile per thread. All dims here divide evenly
// (M=4096, K=1024, N in {128,256,512,1024}).
// ---------------------------------------------------------------------------
template <bool HAS_BIAS>
__global__ __launch_bounds__(256) void gemm_nn(const float* __restrict__ A,
                                               const float* __restrict__ Bm,
                                               const float* __restrict__ bias,
                                               float* __restrict__ C,
                                               int M, int N, int K) {
    constexpr int BM = 128, BN = 128, BK = 8;
    __shared__ float As[BK][BM + 4];   // transposed A tile, padded
    __shared__ float Bs[BK][BN + 4];

    const int tid = threadIdx.x;
    const int bm = blockIdx.y * BM;
    const int bn = blockIdx.x * BN;
    const int tx = tid & 15;   // N direction (16 threads)
    const int ty = tid >> 4;   // M direction (16 threads)

    // staging mappings
    const int arow = tid >> 1;          // 0..127
    const int akq  = (tid & 1) * 4;     // 0 or 4
    const int brow = tid >> 5;          // 0..7
    const int bcol = (tid & 31) * 4;    // 0..124

    float acc[8][8];
#pragma unroll
    for (int i = 0; i < 8; ++i)
#pragma unroll
        for (int j = 0; j < 8; ++j) acc[i][j] = 0.0f;

    const float* Aptr = A + (size_t)(bm + arow) * K + akq;
    const float* Bptr = Bm + (size_t)brow * N + bn + bcol;

    for (int k0 = 0; k0 < K; k0 += BK) {
        float4 a4 = *reinterpret_cast<const float4*>(Aptr + k0);
        float4 b4 = *reinterpret_cast<const float4*>(Bptr + (size_t)k0 * N);
        __syncthreads();
        As[akq + 0][arow] = a4.x;
        As[akq + 1][arow] = a4.y;
        As[akq + 2][arow] = a4.z;
        As[akq + 3][arow] = a4.w;
        *reinterpret_cast<float4*>(&Bs[brow][bcol]) = b4;
        __syncthreads();
#pragma unroll
        for (int k = 0; k < BK; ++k) {
            float4 a0 = *reinterpret_cast<const float4*>(&As[k][ty * 8]);
            float4 a1 = *reinterpret_cast<const float4*>(&As[k][ty * 8 + 4]);
            float4 b0 = *reinterpret_cast<const float4*>(&Bs[k][tx * 4]);
            float4 b1 = *reinterpret_cast<const float4*>(&Bs[k][tx * 4 + 64]);
            float av[8] = {a0.x, a0.y, a0.z, a0.w, a1.x, a1.y, a1.z, a1.w};
            float bv[8] = {b0.x, b0.y, b0.z, b0.w, b1.x, b1.y, b1.z, b1.w};
#pragma unroll
            for (int i = 0; i < 8; ++i)
#pragma unroll
                for (int j = 0; j < 8; ++j) acc[i][j] += av[i] * bv[j];
        }
    }

    float4 bias0 = make_float4(0.f, 0.f, 0.f, 0.f);
    float4 bias1 = make_float4(0.f, 0.f, 0.f, 0.f);
    if (HAS_BIAS) {
        bias0 = *reinterpret_cast<const float4*>(&bias[bn + tx * 4]);
        bias1 = *reinterpret_cast<const float4*>(&bias[bn + 64 + tx * 4]);
    }
#pragma unroll
    for (int i = 0; i < 8; ++i) {
        const size_t row = (size_t)(bm + ty * 8 + i) * N;
        float4 r0, r1;
        r0.x = acc[i][0] + bias0.x;
        r0.y = acc[i][1] + bias0.y;
        r0.z = acc[i][2] + bias0.z;
        r0.w = acc[i][3] + bias0.w;
        r1.x = acc[i][4] + bias1.x;
        r1.y = acc[i][5] + bias1.y;
        r1.z = acc[i][6] + bias1.z;
        r1.w = acc[i][7] + bias1.w;
        *reinterpret_cast<float4*>(&C[row + bn + tx * 4]) = r0;
        *reinterpret_cast<float4*>(&C[row + bn + 64 + tx * 4]) = r1;
    }
}

// ---------------------------------------------------------------------------
// Attention: one thread per query row. Grid (T/256, H, B), 256 threads.
// scores = (q.k + slope*(j-i)) / sqrt(32), causal, softmax, @V.
// No running max needed: scores bounded above by ~+9 (exp never overflows).
// ALiBi decay gives a per-head safe window W = 275/slope (dropped tail
// < e^-38 relative).
// k/v group for head h is (h % 4) because tile() repeats channels.
// ---------------------------------------------------------------------------
__global__ __launch_bounds__(256) void attn_rowwise(const float* __restrict__ qb,
                                                    const float* __restrict__ kb,
                                                    const float* __restrict__ vb,
                                                    float* __restrict__ ctx) {
    const int tid = threadIdx.x;
    const int qb0 = blockIdx.x * 256;
    const int h = blockIdx.y;
    const int b = blockIdx.z;
    const int i = qb0 + tid;
    const int g = h & 3;

    float q[32];
    {
        const float* qrow = qb + ((size_t)(b * T_SEQ + i)) * 512 + h * 32;
#pragma unroll
        for (int d4 = 0; d4 < 8; ++d4) {
            float4 t = *reinterpret_cast<const float4*>(qrow + d4 * 4);
            q[d4 * 4 + 0] = t.x;
            q[d4 * 4 + 1] = t.y;
            q[d4 * 4 + 2] = t.z;
            q[d4 * 4 + 3] = t.w;
        }
    }
    const float slope = exp2f(-0.5f * (float)(h + 1));
    const float scale = 0.17677669529663687f;  // 1/sqrt(32)

    int j0 = qb0 - (int)(275.0f / slope) - 1;
    if (j0 < 0) j0 = 0;
    // per-wave upper bound: last row owned by this wave
    const int jmax = qb0 + ((tid >> 6) + 1) * 64 - 1;

    float l = 0.0f;
    float o[64];
#pragma unroll
    for (int d = 0; d < 64; ++d) o[d] = 0.0f;

    const float* kbase = kb + (size_t)b * T_SEQ * 128 + g * 32;
    const float* vbase = vb + (size_t)b * T_SEQ * 256 + g * 64;

    for (int j = j0; j <= jmax; ++j) {
        const float* krow = kbase + (size_t)j * 128;  // wave-uniform address
        float dot = 0.0f;
#pragma unroll
        for (int d4 = 0; d4 < 8; ++d4) {
            float4 kv = *reinterpret_cast<const float4*>(krow + d4 * 4);
            dot += q[d4 * 4 + 0] * kv.x + q[d4 * 4 + 1] * kv.y +
                   q[d4 * 4 + 2] * kv.z + q[d4 * 4 + 3] * kv.w;
        }
        const float s = (dot + slope * (float)(j - i)) * scale;
        const float p = (j <= i) ? __expf(s) : 0.0f;
        l += p;
        const float* vrow = vbase + (size_t)j * 256;  // wave-uniform address
#pragma unroll
        for (int d4 = 0; d4 < 16; ++d4) {
            float4 vv = *reinterpret_cast<const float4*>(vrow + d4 * 4);
            o[d4 * 4 + 0] += p * vv.x;
            o[d4 * 4 + 1] += p * vv.y;
            o[d4 * 4 + 2] += p * vv.z;
            o[d4 * 4 + 3] += p * vv.w;
        }
    }

    const float inv_l = 1.0f / l;
    float* crow = ctx + ((size_t)(b * T_SEQ + i)) * 1024 + h * 64;
#pragma unroll
    for (int d4 = 0; d4 < 16; ++d4) {
        float4 r;
        r.x = o[d4 * 4 + 0] * inv_l;
        r.y = o[d4 * 4 + 1] * inv_l;
        r.z = o[d4 * 4 + 2] * inv_l;
        r.w = o[d4 * 4 + 3] * inv_l;
        *reinterpret_cast<float4*>(crow + d4 * 4) = r;
    }
}

// ---------------------------------------------------------------------------
extern "C" void kernel_launch(void* const* d_in, const int* in_sizes, int n_in,
                              void* d_out, int out_size, void* d_ws, size_t ws_size,
                              hipStream_t stream) {
    const float* x  = (const float*)d_in[0];
    const float* Wq = (const float*)d_in[1];
    const float* Wk = (const float*)d_in[2];
    const float* Wv = (const float*)d_in[3];
    const float* Wp = (const float*)d_in[4];
    const float* bp = (const float*)d_in[5];
    float* out = (float*)d_out;

    const int M = B_SZ * T_SEQ;  // 4096
    const int K = 1024;

    char* ws = (char*)d_ws;
    float* qbuf = (float*)ws;                                   // 4096 x 512
    float* kbuf = (float*)(ws + (size_t)M * 512 * 4);           // 4096 x 128
    float* vbuf = (float*)(ws + (size_t)M * (512 + 128) * 4);   // 4096 x 256
    float* cbuf = (float*)(ws + (size_t)M * (512 + 128 + 256) * 4);  // 4096 x 1024

    dim3 blk(256);
    gemm_nn<false><<<dim3(512 / 128, M / 128), blk, 0, stream>>>(x, Wq, nullptr, qbuf, M, 512, K);
    gemm_nn<false><<<dim3(128 / 128, M / 128), blk, 0, stream>>>(x, Wk, nullptr, kbuf, M, 128, K);
    gemm_nn<false><<<dim3(256 / 128, M / 128), blk, 0, stream>>>(x, Wv, nullptr, vbuf, M, 256, K);
    attn_rowwise<<<dim3(T_SEQ / 256, H_CNT, B_SZ), blk, 0, stream>>>(qbuf, kbuf, vbuf, cbuf);
    gemm_nn<true><<<dim3(1024 / 128, M / 128), blk, 0, stream>>>(cbuf, Wp, bp, out, M, 1024, K);
}

// Round 2
// 236.692 us; speedup vs baseline: 14.4530x; 14.4530x over previous
//
#include <hip/hip_runtime.h>
#include <hip/hip_bf16.h>

#define T_SEQ 2048
#define H_CNT 16
#define B_SZ  2
#define QKV_LD 896
#define KOFF   512
#define VOFF   640

typedef float  f32x4  __attribute__((ext_vector_type(4)));
typedef __bf16 bf16x8 __attribute__((ext_vector_type(8)));

static __device__ __forceinline__ ushort f2bf(float f) {
    union { float f; unsigned u; } v; v.f = f;
    unsigned u = v.u;
    unsigned r = (u + 0x7fffu + ((u >> 16) & 1u)) >> 16;
    return (ushort)r;
}

static __device__ __forceinline__ f32x4 mfma16(bf16x8 a, bf16x8 b, f32x4 c) {
    return __builtin_amdgcn_mfma_f32_16x16x32_bf16(a, b, c, 0, 0, 0);
}

// ---------------------------------------------------------------------------
// Elementwise fp32 -> bf16 convert (8 elems/thread)
// ---------------------------------------------------------------------------
__global__ __launch_bounds__(256) void convert_bf16(const float* __restrict__ src,
                                                    ushort* __restrict__ dst) {
    const int i = blockIdx.x * 256 + threadIdx.x;
    const float4 v0 = reinterpret_cast<const float4*>(src)[i * 2];
    const float4 v1 = reinterpret_cast<const float4*>(src)[i * 2 + 1];
    uint4 o;
    o.x = (unsigned)f2bf(v0.x) | ((unsigned)f2bf(v0.y) << 16);
    o.y = (unsigned)f2bf(v0.z) | ((unsigned)f2bf(v0.w) << 16);
    o.z = (unsigned)f2bf(v1.x) | ((unsigned)f2bf(v1.y) << 16);
    o.w = (unsigned)f2bf(v1.z) | ((unsigned)f2bf(v1.w) << 16);
    reinterpret_cast<uint4*>(dst)[i] = o;
}

// ---------------------------------------------------------------------------
// Transpose + convert: src fp32 [R][C] -> dst bf16 [C][R].  Block 256 (32x8).
// ---------------------------------------------------------------------------
__global__ __launch_bounds__(256) void transpose_f32_bf16(const float* __restrict__ src,
                                                          ushort* __restrict__ dst,
                                                          int R, int C) {
    __shared__ float tile[32][33];
    const int tx = threadIdx.x & 31, ty = threadIdx.x >> 5;
    const int r0 = blockIdx.y * 32, c0 = blockIdx.x * 32;
#pragma unroll
    for (int i = 0; i < 32; i += 8)
        tile[ty + i][tx] = src[(size_t)(r0 + ty + i) * C + c0 + tx];
    __syncthreads();
#pragma unroll
    for (int i = 0; i < 32; i += 8)
        dst[(size_t)(c0 + ty + i) * R + r0 + tx] = f2bf(tile[tx][ty + i]);
}

// ---------------------------------------------------------------------------
// bf16 strided transpose (for V): dst[z][c][r] = src[z*zoff + r*ld + c]
// ---------------------------------------------------------------------------
__global__ __launch_bounds__(256) void transpose_bf16_str(const ushort* __restrict__ src,
                                                          int src_ld, size_t src_zoff,
                                                          ushort* __restrict__ dst,
                                                          int R, int C, size_t dst_zoff) {
    __shared__ ushort tile[32][33];
    const int tx = threadIdx.x & 31, ty = threadIdx.x >> 5;
    const int r0 = blockIdx.y * 32, c0 = blockIdx.x * 32;
    const ushort* s = src + (size_t)blockIdx.z * src_zoff;
    ushort* d = dst + (size_t)blockIdx.z * dst_zoff;
#pragma unroll
    for (int i = 0; i < 32; i += 8)
        tile[ty + i][tx] = s[(size_t)(r0 + ty + i) * src_ld + c0 + tx];
    __syncthreads();
#pragma unroll
    for (int i = 0; i < 32; i += 8)
        d[(size_t)(c0 + ty + i) * R + r0 + tx] = tile[tx][ty + i];
}

// ---------------------------------------------------------------------------
// bf16 MFMA GEMM: C[M,N] = A[M,K] @ Bt[N,K]^T (+bias).  128x128 tile, BK=32,
// 4 waves (2x2), each wave 64x64 via 4x4 frags of 16x16x32.
// Fragment mappings (m89/m97-verified): A row=lane&15,k=(lane>>4)*8+i;
// B col=lane&15, same k; D col=lane&15,row=(lane>>4)*4+reg.
// ---------------------------------------------------------------------------
template <bool OUT_BF16>
__global__ __launch_bounds__(256) void gemm_bf16(const ushort* __restrict__ A,
                                                 const ushort* __restrict__ Bt,
                                                 const float* __restrict__ bias,
                                                 void* __restrict__ Cout,
                                                 int M, int N, int K) {
    constexpr int LDL = 40;  // padded LDS row stride (80 B: 16B-aligned, ~2-way banks)
    __shared__ __align__(16) ushort As[128 * LDL];
    __shared__ __align__(16) ushort Bs[128 * LDL];

    const int tid = threadIdx.x;
    const int w = tid >> 6, l = tid & 63;
    const int bm = blockIdx.y * 128, bn = blockIdx.x * 128;
    const int wr = (w >> 1) * 64, wc = (w & 1) * 64;
    const int lr = l & 15, lk = (l >> 4) * 8;

    const int sr = tid >> 2;        // staging row 0..63
    const int sc = (tid & 3) * 8;   // staging col (ushorts)

    const ushort* Ap0 = A + (size_t)(bm + sr) * K + sc;
    const ushort* Ap1 = A + (size_t)(bm + 64 + sr) * K + sc;
    const ushort* Bp0 = Bt + (size_t)(bn + sr) * K + sc;
    const ushort* Bp1 = Bt + (size_t)(bn + 64 + sr) * K + sc;

    f32x4 acc[4][4];
#pragma unroll
    for (int m = 0; m < 4; ++m)
#pragma unroll
        for (int n = 0; n < 4; ++n) acc[m][n] = (f32x4){0.f, 0.f, 0.f, 0.f};

    for (int k0 = 0; k0 < K; k0 += 32) {
        uint4 a0 = *reinterpret_cast<const uint4*>(Ap0 + k0);
        uint4 a1 = *reinterpret_cast<const uint4*>(Ap1 + k0);
        uint4 b0 = *reinterpret_cast<const uint4*>(Bp0 + k0);
        uint4 b1 = *reinterpret_cast<const uint4*>(Bp1 + k0);
        if (k0) __syncthreads();
        *reinterpret_cast<uint4*>(&As[sr * LDL + sc]) = a0;
        *reinterpret_cast<uint4*>(&As[(64 + sr) * LDL + sc]) = a1;
        *reinterpret_cast<uint4*>(&Bs[sr * LDL + sc]) = b0;
        *reinterpret_cast<uint4*>(&Bs[(64 + sr) * LDL + sc]) = b1;
        __syncthreads();

        bf16x8 af[4], bfr[4];
#pragma unroll
        for (int m = 0; m < 4; ++m)
            af[m] = *reinterpret_cast<const bf16x8*>(&As[(wr + m * 16 + lr) * LDL + lk]);
#pragma unroll
        for (int n = 0; n < 4; ++n)
            bfr[n] = *reinterpret_cast<const bf16x8*>(&Bs[(wc + n * 16 + lr) * LDL + lk]);
#pragma unroll
        for (int m = 0; m < 4; ++m)
#pragma unroll
            for (int n = 0; n < 4; ++n)
                acc[m][n] = mfma16(af[m], bfr[n], acc[m][n]);
    }

    const int orow = bm + wr + (l >> 4) * 4;
    const int ocol0 = bn + wc + lr;
#pragma unroll
    for (int m = 0; m < 4; ++m)
#pragma unroll
        for (int n = 0; n < 4; ++n) {
            const int col = ocol0 + n * 16;
            const float bv = OUT_BF16 ? 0.0f : bias[col];
#pragma unroll
            for (int r = 0; r < 4; ++r) {
                const size_t idx = (size_t)(orow + m * 16 + r) * N + col;
                if constexpr (OUT_BF16)
                    reinterpret_cast<ushort*>(Cout)[idx] = f2bf(acc[m][n][r]);
                else
                    reinterpret_cast<float*>(Cout)[idx] = acc[m][n][r] + bv;
            }
        }
}

// ---------------------------------------------------------------------------
// Flash attention, bf16 MFMA. Block = 4 waves; wave = 16 q-rows; KBLK = 32.
// qkv: [B*T][896] bf16 (q|k|v packed); vT: [B][256][T] bf16; ctx: [B*T][1024].
// Per (b,h): K-group g=h&3. No running max (scores bounded; validated R1).
// ---------------------------------------------------------------------------
__global__ __launch_bounds__(256) void attn_mfma(const ushort* __restrict__ qkv,
                                                 const ushort* __restrict__ vT,
                                                 ushort* __restrict__ ctx) {
    __shared__ __align__(16) ushort P_lds[4][16][40];
    const int tid = threadIdx.x;
    const int w = tid >> 6, l = tid & 63;
    const int h = blockIdx.y, b = blockIdx.z;
    const int i0 = blockIdx.x * 64 + w * 16;
    const int g = h & 3;
    const int lr = l & 15, lg = l >> 4;

    const float slope = exp2f(-0.5f * (float)(h + 1));
    const float scale = 0.17677669529663687f;  // 1/sqrt(32)

    // Q fragment (row = i0+lr, dq = lg*8..+7)
    const bf16x8 qf = *reinterpret_cast<const bf16x8*>(
        &qkv[((size_t)(b * T_SEQ + i0 + lr)) * QKV_LD + h * 32 + lg * 8]);

    const ushort* kb = qkv + (size_t)b * T_SEQ * QKV_LD + KOFF + g * 32;
    const ushort* vb = vT + ((size_t)b * 256 + g * 64) * T_SEQ;

    f32x4 o[4];
#pragma unroll
    for (int n = 0; n < 4; ++n) o[n] = (f32x4){0.f, 0.f, 0.f, 0.f};
    float lsum[4] = {0.f, 0.f, 0.f, 0.f};

    int jt0;
    {
        int j0 = i0 - (int)(275.0f / slope);
        if (j0 < 0) j0 = 0;
        jt0 = (j0 >> 5) << 5;
    }
    const int jend = i0 + 16;

    for (int jt = jt0; jt < jend; jt += 32) {
        float p[2][4];
#pragma unroll
        for (int t = 0; t < 2; ++t) {
            const int jj = jt + t * 16 + lr;  // this lane's key column
            bf16x8 kf = *reinterpret_cast<const bf16x8*>(&kb[(size_t)jj * QKV_LD + lg * 8]);
            f32x4 s = (f32x4){0.f, 0.f, 0.f, 0.f};
            s = mfma16(qf, kf, s);
#pragma unroll
            for (int r = 0; r < 4; ++r) {
                const int i = i0 + lg * 4 + r;
                const float sc = (s[r] + slope * (float)(jj - i)) * scale;
                const float pv = (jj <= i) ? __expf(sc) : 0.0f;
                p[t][r] = pv;
                lsum[r] += pv;
            }
        }
        // P -> LDS (bf16), per-wave buffer; wave-in-order ds ops, no barrier.
#pragma unroll
        for (int t = 0; t < 2; ++t)
#pragma unroll
            for (int r = 0; r < 4; ++r)
                P_lds[w][lg * 4 + r][t * 16 + lr] = f2bf(p[t][r]);
        const bf16x8 pf = *reinterpret_cast<const bf16x8*>(&P_lds[w][lr][lg * 8]);
#pragma unroll
        for (int n = 0; n < 4; ++n) {
            bf16x8 vf = *reinterpret_cast<const bf16x8*>(
                &vb[(size_t)(n * 16 + lr) * T_SEQ + jt + lg * 8]);
            o[n] = mfma16(pf, vf, o[n]);
        }
    }

    // row-sum reduce across the 16 lanes of each lg-group
#pragma unroll
    for (int r = 0; r < 4; ++r) {
        float v = lsum[r];
        v += __shfl_xor(v, 1);
        v += __shfl_xor(v, 2);
        v += __shfl_xor(v, 4);
        v += __shfl_xor(v, 8);
        lsum[r] = 1.0f / v;
    }
#pragma unroll
    for (int n = 0; n < 4; ++n)
#pragma unroll
        for (int r = 0; r < 4; ++r) {
            const size_t row = (size_t)(b * T_SEQ + i0 + lg * 4 + r);
            ctx[row * 1024 + h * 64 + n * 16 + lr] = f2bf(o[n][r] * lsum[r]);
        }
}

// ---------------------------------------------------------------------------
extern "C" void kernel_launch(void* const* d_in, const int* in_sizes, int n_in,
                              void* d_out, int out_size, void* d_ws, size_t ws_size,
                              hipStream_t stream) {
    const float* x  = (const float*)d_in[0];
    const float* Wq = (const float*)d_in[1];
    const float* Wk = (const float*)d_in[2];
    const float* Wv = (const float*)d_in[3];
    const float* Wp = (const float*)d_in[4];
    const float* bp = (const float*)d_in[5];

    const int M = B_SZ * T_SEQ;  // 4096

    ushort* ws    = (ushort*)d_ws;
    ushort* xb    = ws;                   // 4096x1024
    ushort* Wqkvt = xb + 4194304;         // 896x1024 (rows: Wq^T | Wk^T | Wv^T)
    ushort* Wpt   = Wqkvt + 917504;       // 1024x1024
    ushort* qkv   = Wpt + 1048576;        // 4096x896
    ushort* vTb   = qkv + 3670016;        // 2x256x2048
    ushort* cbuf  = vTb + 1048576;        // 4096x1024

    convert_bf16<<<2048, 256, 0, stream>>>(x, xb);
    transpose_f32_bf16<<<dim3(16, 32), 256, 0, stream>>>(Wq, Wqkvt, 1024, 512);
    transpose_f32_bf16<<<dim3(4, 32), 256, 0, stream>>>(Wk, Wqkvt + 512 * 1024, 1024, 128);
    transpose_f32_bf16<<<dim3(8, 32), 256, 0, stream>>>(Wv, Wqkvt + 640 * 1024, 1024, 256);
    transpose_f32_bf16<<<dim3(32, 32), 256, 0, stream>>>(Wp, Wpt, 1024, 1024);

    gemm_bf16<true><<<dim3(7, 32), 256, 0, stream>>>(xb, Wqkvt, nullptr, qkv, M, 896, 1024);

    transpose_bf16_str<<<dim3(8, 64, 2), 256, 0, stream>>>(
        qkv + VOFF, QKV_LD, (size_t)T_SEQ * QKV_LD, vTb, T_SEQ, 256, (size_t)256 * T_SEQ);

    attn_mfma<<<dim3(T_SEQ / 64, H_CNT, B_SZ), 256, 0, stream>>>(qkv, vTb, cbuf);

    gemm_bf16<false><<<dim3(8, 32), 256, 0, stream>>>(cbuf, Wpt, bp, (float*)d_out, M, 1024, 1024);
}

// Round 3
// 140.254 us; speedup vs baseline: 24.3908x; 1.6876x over previous
//
#include <hip/hip_runtime.h>
#include <hip/hip_bf16.h>

#define T_SEQ 2048
#define H_CNT 16
#define B_SZ  2
#define QKV_LD 896
#define KOFF   512
#define VOFF   640

typedef float  f32x4  __attribute__((ext_vector_type(4)));
typedef __bf16 bf16x8 __attribute__((ext_vector_type(8)));

static __device__ __forceinline__ ushort f2bf(float f) {
    union { float f; unsigned u; } v; v.f = f;
    unsigned u = v.u;
    unsigned r = (u + 0x7fffu + ((u >> 16) & 1u)) >> 16;
    return (ushort)r;
}
static __device__ __forceinline__ ushort f2bf_fast(float f) {
    union { float f; unsigned u; } v; v.f = f;
    return (ushort)((v.u + 0x8000u) >> 16);
}

static __device__ __forceinline__ f32x4 mfma16(bf16x8 a, bf16x8 b, f32x4 c) {
    return __builtin_amdgcn_mfma_f32_16x16x32_bf16(a, b, c, 0, 0, 0);
}

// ---------------------------------------------------------------------------
// Elementwise fp32 -> bf16 convert (8 elems/thread)
// ---------------------------------------------------------------------------
__global__ __launch_bounds__(256) void convert_bf16(const float* __restrict__ src,
                                                    ushort* __restrict__ dst) {
    const int i = blockIdx.x * 256 + threadIdx.x;
    const float4 v0 = reinterpret_cast<const float4*>(src)[i * 2];
    const float4 v1 = reinterpret_cast<const float4*>(src)[i * 2 + 1];
    uint4 o;
    o.x = (unsigned)f2bf(v0.x) | ((unsigned)f2bf(v0.y) << 16);
    o.y = (unsigned)f2bf(v0.z) | ((unsigned)f2bf(v0.w) << 16);
    o.z = (unsigned)f2bf(v1.x) | ((unsigned)f2bf(v1.y) << 16);
    o.w = (unsigned)f2bf(v1.z) | ((unsigned)f2bf(v1.w) << 16);
    reinterpret_cast<uint4*>(dst)[i] = o;
}

// ---------------------------------------------------------------------------
// Transpose + convert: src fp32 [R][C] -> dst bf16 [C][R].  Block 256 (32x8).
// ---------------------------------------------------------------------------
__global__ __launch_bounds__(256) void transpose_f32_bf16(const float* __restrict__ src,
                                                          ushort* __restrict__ dst,
                                                          int R, int C) {
    __shared__ float tile[32][33];
    const int tx = threadIdx.x & 31, ty = threadIdx.x >> 5;
    const int r0 = blockIdx.y * 32, c0 = blockIdx.x * 32;
#pragma unroll
    for (int i = 0; i < 32; i += 8)
        tile[ty + i][tx] = src[(size_t)(r0 + ty + i) * C + c0 + tx];
    __syncthreads();
#pragma unroll
    for (int i = 0; i < 32; i += 8)
        dst[(size_t)(c0 + ty + i) * R + r0 + tx] = f2bf(tile[tx][ty + i]);
}

// ---------------------------------------------------------------------------
// bf16 strided transpose (for V): dst[z][c][r] = src[z*zoff + r*ld + c]
// ---------------------------------------------------------------------------
__global__ __launch_bounds__(256) void transpose_bf16_str(const ushort* __restrict__ src,
                                                          int src_ld, size_t src_zoff,
                                                          ushort* __restrict__ dst,
                                                          int R, int C, size_t dst_zoff) {
    __shared__ ushort tile[32][33];
    const int tx = threadIdx.x & 31, ty = threadIdx.x >> 5;
    const int r0 = blockIdx.y * 32, c0 = blockIdx.x * 32;
    const ushort* s = src + (size_t)blockIdx.z * src_zoff;
    ushort* d = dst + (size_t)blockIdx.z * dst_zoff;
#pragma unroll
    for (int i = 0; i < 32; i += 8)
        tile[ty + i][tx] = s[(size_t)(r0 + ty + i) * src_ld + c0 + tx];
    __syncthreads();
#pragma unroll
    for (int i = 0; i < 32; i += 8)
        d[(size_t)(c0 + ty + i) * R + r0 + tx] = tile[tx][ty + i];
}

// ---------------------------------------------------------------------------
// bf16 MFMA GEMM with register prefetch: C[M,N] = A[M,K] @ Bt[N,K]^T (+bias).
// 128x128 tile, BK=32, 4 waves (2x2), each wave 64x64 via 4x4 frags.
// ---------------------------------------------------------------------------
template <bool OUT_BF16>
__global__ __launch_bounds__(256) void gemm_bf16(const ushort* __restrict__ A,
                                                 const ushort* __restrict__ Bt,
                                                 const float* __restrict__ bias,
                                                 void* __restrict__ Cout,
                                                 int M, int N, int K) {
    constexpr int LDL = 40;
    __shared__ __align__(16) ushort As[128 * LDL];
    __shared__ __align__(16) ushort Bs[128 * LDL];

    const int tid = threadIdx.x;
    const int w = tid >> 6, l = tid & 63;
    const int bm = blockIdx.y * 128, bn = blockIdx.x * 128;
    const int wr = (w >> 1) * 64, wc = (w & 1) * 64;
    const int lr = l & 15, lk = (l >> 4) * 8;

    const int sr = tid >> 2;
    const int sc = (tid & 3) * 8;

    const ushort* Ap0 = A + (size_t)(bm + sr) * K + sc;
    const ushort* Ap1 = A + (size_t)(bm + 64 + sr) * K + sc;
    const ushort* Bp0 = Bt + (size_t)(bn + sr) * K + sc;
    const ushort* Bp1 = Bt + (size_t)(bn + 64 + sr) * K + sc;

    f32x4 acc[4][4];
#pragma unroll
    for (int m = 0; m < 4; ++m)
#pragma unroll
        for (int n = 0; n < 4; ++n) acc[m][n] = (f32x4){0.f, 0.f, 0.f, 0.f};

    uint4 a0 = *reinterpret_cast<const uint4*>(Ap0);
    uint4 a1 = *reinterpret_cast<const uint4*>(Ap1);
    uint4 b0 = *reinterpret_cast<const uint4*>(Bp0);
    uint4 b1 = *reinterpret_cast<const uint4*>(Bp1);

    for (int k0 = 0; k0 < K; k0 += 32) {
        if (k0) __syncthreads();
        *reinterpret_cast<uint4*>(&As[sr * LDL + sc]) = a0;
        *reinterpret_cast<uint4*>(&As[(64 + sr) * LDL + sc]) = a1;
        *reinterpret_cast<uint4*>(&Bs[sr * LDL + sc]) = b0;
        *reinterpret_cast<uint4*>(&Bs[(64 + sr) * LDL + sc]) = b1;
        __syncthreads();
        if (k0 + 32 < K) {
            a0 = *reinterpret_cast<const uint4*>(Ap0 + k0 + 32);
            a1 = *reinterpret_cast<const uint4*>(Ap1 + k0 + 32);
            b0 = *reinterpret_cast<const uint4*>(Bp0 + k0 + 32);
            b1 = *reinterpret_cast<const uint4*>(Bp1 + k0 + 32);
        }
        bf16x8 af[4], bfr[4];
#pragma unroll
        for (int m = 0; m < 4; ++m)
            af[m] = *reinterpret_cast<const bf16x8*>(&As[(wr + m * 16 + lr) * LDL + lk]);
#pragma unroll
        for (int n = 0; n < 4; ++n)
            bfr[n] = *reinterpret_cast<const bf16x8*>(&Bs[(wc + n * 16 + lr) * LDL + lk]);
#pragma unroll
        for (int m = 0; m < 4; ++m)
#pragma unroll
            for (int n = 0; n < 4; ++n)
                acc[m][n] = mfma16(af[m], bfr[n], acc[m][n]);
    }

    const int orow = bm + wr + (l >> 4) * 4;
    const int ocol0 = bn + wc + lr;
#pragma unroll
    for (int m = 0; m < 4; ++m)
#pragma unroll
        for (int n = 0; n < 4; ++n) {
            const int col = ocol0 + n * 16;
            const float bv = OUT_BF16 ? 0.0f : bias[col];
#pragma unroll
            for (int r = 0; r < 4; ++r) {
                const size_t idx = (size_t)(orow + m * 16 + r) * N + col;
                if constexpr (OUT_BF16)
                    reinterpret_cast<ushort*>(Cout)[idx] = f2bf(acc[m][n][r]);
                else
                    reinterpret_cast<float*>(Cout)[idx] = acc[m][n][r] + bv;
            }
        }
}

// ---------------------------------------------------------------------------
// Flash attention v2: block = (b, h, 128 q-rows) with 4 waves x 32 q-rows.
// KV tiles of 64 keys staged in LDS (shared by all waves), reg-prefetched.
// K_lds [64][40] (key-major), V_lds [64][72] (d-major = V^T tile),
// P_lds per-wave [32][72]. 16x16x32 MFMA, softmax in log2 domain, no
// running max (scores bounded; validated R1/R2).
// ---------------------------------------------------------------------------
#define LDK 40
#define LDV 72
#define LDP 72

__global__ __launch_bounds__(256) void attn_mfma2(const ushort* __restrict__ qkv,
                                                  const ushort* __restrict__ vT,
                                                  ushort* __restrict__ ctx) {
    __shared__ __align__(16) ushort Ks[64 * LDK];
    __shared__ __align__(16) ushort Vs[64 * LDV];
    __shared__ __align__(16) ushort Ps[4][32 * LDP];

    const int tid = threadIdx.x;
    const int w = tid >> 6, l = tid & 63;
    const int lr = l & 15, lg = l >> 4;
    const int h = blockIdx.y, b = blockIdx.z;
    const int i0 = blockIdx.x * 128;
    const int i0w = i0 + w * 32;
    const int g = h & 3;

    const float slope = exp2f(-0.5f * (float)(h + 1));
    const float k1 = 0.17677669529663687f * 1.4426950408889634f;  // scale*log2e
    const float k2 = slope * k1;

    // Q fragments (rows i0w + qm*16 + lr, dq = lg*8 .. +7)
    bf16x8 qf[2];
#pragma unroll
    for (int qm = 0; qm < 2; ++qm)
        qf[qm] = *reinterpret_cast<const bf16x8*>(
            &qkv[((size_t)(b * T_SEQ + i0w + qm * 16 + lr)) * QKV_LD + h * 32 + lg * 8]);

    // staging mappings (256 threads)
    const int sd = tid >> 2;         // key row (K) / d row (V), 0..63
    const int sc = (tid & 3) * 8;    // 8-elem chunk
    const ushort* kgp = qkv + (size_t)b * T_SEQ * QKV_LD + KOFF + g * 32 + (size_t)sd * QKV_LD + sc;
    const ushort* vgp = vT + ((size_t)b * 256 + g * 64 + sd) * T_SEQ + sc;

    int jt0 = i0 - (int)(275.0f / slope);
    if (jt0 < 0) jt0 = 0;
    jt0 &= ~63;
    const int jtend = i0 + 128;

    f32x4 o[2][4];
#pragma unroll
    for (int qm = 0; qm < 2; ++qm)
#pragma unroll
        for (int n = 0; n < 4; ++n) o[qm][n] = (f32x4){0.f, 0.f, 0.f, 0.f};
    float lsum[2][4] = {{0.f, 0.f, 0.f, 0.f}, {0.f, 0.f, 0.f, 0.f}};

    // preload first tile
    uint4 kreg = *reinterpret_cast<const uint4*>(kgp + (size_t)jt0 * QKV_LD);
    uint4 vreg0 = *reinterpret_cast<const uint4*>(vgp + jt0);
    uint4 vreg1 = *reinterpret_cast<const uint4*>(vgp + jt0 + 32);

    for (int jt = jt0; jt < jtend; jt += 64) {
        __syncthreads();
        *reinterpret_cast<uint4*>(&Ks[sd * LDK + sc]) = kreg;
        *reinterpret_cast<uint4*>(&Vs[sd * LDV + sc]) = vreg0;
        *reinterpret_cast<uint4*>(&Vs[sd * LDV + 32 + sc]) = vreg1;
        __syncthreads();
        const int jn = jt + 64;
        if (jn < jtend) {
            kreg = *reinterpret_cast<const uint4*>(kgp + (size_t)jn * QKV_LD);
            vreg0 = *reinterpret_cast<const uint4*>(vgp + jn);
            vreg1 = *reinterpret_cast<const uint4*>(vgp + jn + 32);
        }
        if (jt > i0w + 31) continue;  // beyond this wave's causal end (barriers stay uniform)

        // ---- QK^T ----
        bf16x8 kf[4];
#pragma unroll
        for (int kn = 0; kn < 4; ++kn)
            kf[kn] = *reinterpret_cast<const bf16x8*>(&Ks[(kn * 16 + lr) * LDK + lg * 8]);
        f32x4 s[2][4];
#pragma unroll
        for (int qm = 0; qm < 2; ++qm)
#pragma unroll
            for (int kn = 0; kn < 4; ++kn) {
                s[qm][kn] = (f32x4){0.f, 0.f, 0.f, 0.f};
                s[qm][kn] = mfma16(qf[qm], kf[kn], s[qm][kn]);
            }

        // ---- softmax weights (log2 domain) ----
        const bool diag = (jt + 64 > i0w);
        const int dj = jt + lr - i0w - lg * 4;   // j - q, before (kn-qm)*16 - r
        const float fb = (float)dj * k2;
#pragma unroll
        for (int qm = 0; qm < 2; ++qm)
#pragma unroll
            for (int kn = 0; kn < 4; ++kn)
#pragma unroll
                for (int r = 0; r < 4; ++r) {
                    const int icc = (kn - qm) * 16 - r;
                    const float arg = fmaf(s[qm][kn][r], k1, fmaf((float)icc, k2, fb));
                    float p = exp2f(arg);
                    if (diag && (dj + icc > 0)) p = 0.0f;
                    lsum[qm][r] += p;
                    Ps[w][(qm * 16 + lg * 4 + r) * LDP + kn * 16 + lr] = f2bf_fast(p);
                }

        // ---- PV ----
        bf16x8 pf[2][2];
#pragma unroll
        for (int qm = 0; qm < 2; ++qm)
#pragma unroll
            for (int kk = 0; kk < 2; ++kk)
                pf[qm][kk] = *reinterpret_cast<const bf16x8*>(
                    &Ps[w][(qm * 16 + lr) * LDP + kk * 32 + lg * 8]);
#pragma unroll
        for (int kk = 0; kk < 2; ++kk)
#pragma unroll
            for (int dn = 0; dn < 4; ++dn) {
                const bf16x8 vf = *reinterpret_cast<const bf16x8*>(
                    &Vs[(dn * 16 + lr) * LDV + kk * 32 + lg * 8]);
#pragma unroll
                for (int qm = 0; qm < 2; ++qm)
                    o[qm][dn] = mfma16(pf[qm][kk], vf, o[qm][dn]);
            }
    }

    // ---- normalize + write ----
    float inv[2][4];
#pragma unroll
    for (int qm = 0; qm < 2; ++qm)
#pragma unroll
        for (int r = 0; r < 4; ++r) {
            float v = lsum[qm][r];
            v += __shfl_xor(v, 1);
            v += __shfl_xor(v, 2);
            v += __shfl_xor(v, 4);
            v += __shfl_xor(v, 8);
            inv[qm][r] = 1.0f / v;
        }
#pragma unroll
    for (int qm = 0; qm < 2; ++qm)
#pragma unroll
        for (int dn = 0; dn < 4; ++dn)
#pragma unroll
            for (int r = 0; r < 4; ++r) {
                const size_t row = (size_t)(b * T_SEQ + i0w + qm * 16 + lg * 4 + r);
                ctx[row * 1024 + h * 64 + dn * 16 + lr] = f2bf(o[qm][dn][r] * inv[qm][r]);
            }
}

// ---------------------------------------------------------------------------
extern "C" void kernel_launch(void* const* d_in, const int* in_sizes, int n_in,
                              void* d_out, int out_size, void* d_ws, size_t ws_size,
                              hipStream_t stream) {
    const float* x  = (const float*)d_in[0];
    const float* Wq = (const float*)d_in[1];
    const float* Wk = (const float*)d_in[2];
    const float* Wv = (const float*)d_in[3];
    const float* Wp = (const float*)d_in[4];
    const float* bp = (const float*)d_in[5];

    const int M = B_SZ * T_SEQ;  // 4096

    ushort* ws    = (ushort*)d_ws;
    ushort* xb    = ws;                   // 4096x1024
    ushort* Wqkvt = xb + 4194304;         // 896x1024 (rows: Wq^T | Wk^T | Wv^T)
    ushort* Wpt   = Wqkvt + 917504;       // 1024x1024
    ushort* qkv   = Wpt + 1048576;        // 4096x896
    ushort* vTb   = qkv + 3670016;        // 2x256x2048
    ushort* cbuf  = vTb + 1048576;        // 4096x1024

    convert_bf16<<<2048, 256, 0, stream>>>(x, xb);
    transpose_f32_bf16<<<dim3(16, 32), 256, 0, stream>>>(Wq, Wqkvt, 1024, 512);
    transpose_f32_bf16<<<dim3(4, 32), 256, 0, stream>>>(Wk, Wqkvt + 512 * 1024, 1024, 128);
    transpose_f32_bf16<<<dim3(8, 32), 256, 0, stream>>>(Wv, Wqkvt + 640 * 1024, 1024, 256);
    transpose_f32_bf16<<<dim3(32, 32), 256, 0, stream>>>(Wp, Wpt, 1024, 1024);

    gemm_bf16<true><<<dim3(7, 32), 256, 0, stream>>>(xb, Wqkvt, nullptr, qkv, M, 896, 1024);

    transpose_bf16_str<<<dim3(8, 64, 2), 256, 0, stream>>>(
        qkv + VOFF, QKV_LD, (size_t)T_SEQ * QKV_LD, vTb, T_SEQ, 256, (size_t)256 * T_SEQ);

    attn_mfma2<<<dim3(T_SEQ / 128, H_CNT, B_SZ), 256, 0, stream>>>(qkv, vTb, cbuf);

    gemm_bf16<false><<<dim3(8, 32), 256, 0, stream>>>(cbuf, Wpt, bp, (float*)d_out, M, 1024, 1024);
}

// Round 4
// 131.759 us; speedup vs baseline: 25.9633x; 1.0645x over previous
//
#include <hip/hip_runtime.h>
#include <hip/hip_bf16.h>

#define T_SEQ 2048
#define H_CNT 16
#define B_SZ  2
#define QKV_LD 896
#define KOFF   512
#define VOFF   640

typedef float  f32x4   __attribute__((ext_vector_type(4)));
typedef float  f32x16  __attribute__((ext_vector_type(16)));
typedef __bf16 bf16x8  __attribute__((ext_vector_type(8)));

static __device__ __forceinline__ ushort f2bf(float f) {
    union { float f; unsigned u; } v; v.f = f;
    unsigned u = v.u;
    unsigned r = (u + 0x7fffu + ((u >> 16) & 1u)) >> 16;
    return (ushort)r;
}
static __device__ __forceinline__ unsigned pack2bf(float a, float b) {
    union { __bf16 h[2]; unsigned u; } pk;
    pk.h[0] = (__bf16)a; pk.h[1] = (__bf16)b;
    return pk.u;
}

static __device__ __forceinline__ f32x4 mfma16(bf16x8 a, bf16x8 b, f32x4 c) {
    return __builtin_amdgcn_mfma_f32_16x16x32_bf16(a, b, c, 0, 0, 0);
}
static __device__ __forceinline__ f32x16 mfma32(bf16x8 a, bf16x8 b, f32x16 c) {
    return __builtin_amdgcn_mfma_f32_32x32x16_bf16(a, b, c, 0, 0, 0);
}

// ---------------------------------------------------------------------------
// Elementwise fp32 -> bf16 convert (8 elems/thread)
// ---------------------------------------------------------------------------
__global__ __launch_bounds__(256) void convert_bf16(const float* __restrict__ src,
                                                    ushort* __restrict__ dst) {
    const int i = blockIdx.x * 256 + threadIdx.x;
    const float4 v0 = reinterpret_cast<const float4*>(src)[i * 2];
    const float4 v1 = reinterpret_cast<const float4*>(src)[i * 2 + 1];
    uint4 o;
    o.x = (unsigned)f2bf(v0.x) | ((unsigned)f2bf(v0.y) << 16);
    o.y = (unsigned)f2bf(v0.z) | ((unsigned)f2bf(v0.w) << 16);
    o.z = (unsigned)f2bf(v1.x) | ((unsigned)f2bf(v1.y) << 16);
    o.w = (unsigned)f2bf(v1.z) | ((unsigned)f2bf(v1.w) << 16);
    reinterpret_cast<uint4*>(dst)[i] = o;
}

// ---------------------------------------------------------------------------
// All 4 weight transposes merged: fp32 [1024][C] -> bf16 [C][1024].
// grid (60, 32): x<16 Wq, <20 Wk, <28 Wv, else Wp.
// ---------------------------------------------------------------------------
__global__ __launch_bounds__(256) void prep_weights(const float* __restrict__ Wq,
                                                    const float* __restrict__ Wk,
                                                    const float* __restrict__ Wv,
                                                    const float* __restrict__ Wp,
                                                    ushort* __restrict__ Wqkvt,
                                                    ushort* __restrict__ Wpt) {
    __shared__ float tile[32][33];
    const int x = blockIdx.x;
    const float* src; ushort* dst; int C, cx;
    if (x < 16)      { src = Wq; dst = Wqkvt;              C = 512;  cx = x; }
    else if (x < 20) { src = Wk; dst = Wqkvt + 512 * 1024; C = 128;  cx = x - 16; }
    else if (x < 28) { src = Wv; dst = Wqkvt + 640 * 1024; C = 256;  cx = x - 20; }
    else             { src = Wp; dst = Wpt;                C = 1024; cx = x - 28; }
    const int tx = threadIdx.x & 31, ty = threadIdx.x >> 5;
    const int r0 = blockIdx.y * 32, c0 = cx * 32;
#pragma unroll
    for (int i = 0; i < 32; i += 8)
        tile[ty + i][tx] = src[(size_t)(r0 + ty + i) * C + c0 + tx];
    __syncthreads();
#pragma unroll
    for (int i = 0; i < 32; i += 8)
        dst[(size_t)(c0 + ty + i) * 1024 + r0 + tx] = f2bf(tile[tx][ty + i]);
}

// ---------------------------------------------------------------------------
// bf16 strided transpose (for V): dst[z][c][r] = src[z*zoff + r*ld + c]
// ---------------------------------------------------------------------------
__global__ __launch_bounds__(256) void transpose_bf16_str(const ushort* __restrict__ src,
                                                          int src_ld, size_t src_zoff,
                                                          ushort* __restrict__ dst,
                                                          int R, int C, size_t dst_zoff) {
    __shared__ ushort tile[32][33];
    const int tx = threadIdx.x & 31, ty = threadIdx.x >> 5;
    const int r0 = blockIdx.y * 32, c0 = blockIdx.x * 32;
    const ushort* s = src + (size_t)blockIdx.z * src_zoff;
    ushort* d = dst + (size_t)blockIdx.z * dst_zoff;
#pragma unroll
    for (int i = 0; i < 32; i += 8)
        tile[ty + i][tx] = s[(size_t)(r0 + ty + i) * src_ld + c0 + tx];
    __syncthreads();
#pragma unroll
    for (int i = 0; i < 32; i += 8)
        d[(size_t)(c0 + ty + i) * R + r0 + tx] = tile[tx][ty + i];
}

// ---------------------------------------------------------------------------
// bf16 MFMA GEMM with register prefetch: C[M,N] = A[M,K] @ Bt[N,K]^T (+bias).
// 128x128 tile, BK=32, 4 waves (2x2), each wave 64x64 via 4x4 frags of 16x16x32.
// ---------------------------------------------------------------------------
template <bool OUT_BF16>
__global__ __launch_bounds__(256) void gemm_bf16(const ushort* __restrict__ A,
                                                 const ushort* __restrict__ Bt,
                                                 const float* __restrict__ bias,
                                                 void* __restrict__ Cout,
                                                 int M, int N, int K) {
    constexpr int LDL = 40;
    __shared__ __align__(16) ushort As[128 * LDL];
    __shared__ __align__(16) ushort Bs[128 * LDL];

    const int tid = threadIdx.x;
    const int w = tid >> 6, l = tid & 63;
    const int bm = blockIdx.y * 128, bn = blockIdx.x * 128;
    const int wr = (w >> 1) * 64, wc = (w & 1) * 64;
    const int lr = l & 15, lk = (l >> 4) * 8;

    const int sr = tid >> 2;
    const int sc = (tid & 3) * 8;

    const ushort* Ap0 = A + (size_t)(bm + sr) * K + sc;
    const ushort* Ap1 = A + (size_t)(bm + 64 + sr) * K + sc;
    const ushort* Bp0 = Bt + (size_t)(bn + sr) * K + sc;
    const ushort* Bp1 = Bt + (size_t)(bn + 64 + sr) * K + sc;

    f32x4 acc[4][4];
#pragma unroll
    for (int m = 0; m < 4; ++m)
#pragma unroll
        for (int n = 0; n < 4; ++n) acc[m][n] = (f32x4){0.f, 0.f, 0.f, 0.f};

    uint4 a0 = *reinterpret_cast<const uint4*>(Ap0);
    uint4 a1 = *reinterpret_cast<const uint4*>(Ap1);
    uint4 b0 = *reinterpret_cast<const uint4*>(Bp0);
    uint4 b1 = *reinterpret_cast<const uint4*>(Bp1);

    for (int k0 = 0; k0 < K; k0 += 32) {
        if (k0) __syncthreads();
        *reinterpret_cast<uint4*>(&As[sr * LDL + sc]) = a0;
        *reinterpret_cast<uint4*>(&As[(64 + sr) * LDL + sc]) = a1;
        *reinterpret_cast<uint4*>(&Bs[sr * LDL + sc]) = b0;
        *reinterpret_cast<uint4*>(&Bs[(64 + sr) * LDL + sc]) = b1;
        __syncthreads();
        if (k0 + 32 < K) {
            a0 = *reinterpret_cast<const uint4*>(Ap0 + k0 + 32);
            a1 = *reinterpret_cast<const uint4*>(Ap1 + k0 + 32);
            b0 = *reinterpret_cast<const uint4*>(Bp0 + k0 + 32);
            b1 = *reinterpret_cast<const uint4*>(Bp1 + k0 + 32);
        }
        bf16x8 af[4], bfr[4];
#pragma unroll
        for (int m = 0; m < 4; ++m)
            af[m] = *reinterpret_cast<const bf16x8*>(&As[(wr + m * 16 + lr) * LDL + lk]);
#pragma unroll
        for (int n = 0; n < 4; ++n)
            bfr[n] = *reinterpret_cast<const bf16x8*>(&Bs[(wc + n * 16 + lr) * LDL + lk]);
#pragma unroll
        for (int m = 0; m < 4; ++m)
#pragma unroll
            for (int n = 0; n < 4; ++n)
                acc[m][n] = mfma16(af[m], bfr[n], acc[m][n]);
    }

    const int orow = bm + wr + (l >> 4) * 4;
    const int ocol0 = bn + wc + lr;
#pragma unroll
    for (int m = 0; m < 4; ++m)
#pragma unroll
        for (int n = 0; n < 4; ++n) {
            const int col = ocol0 + n * 16;
            const float bv = OUT_BF16 ? 0.0f : bias[col];
#pragma unroll
            for (int r = 0; r < 4; ++r) {
                const size_t idx = (size_t)(orow + m * 16 + r) * N + col;
                if constexpr (OUT_BF16)
                    reinterpret_cast<ushort*>(Cout)[idx] = f2bf(acc[m][n][r]);
                else
                    reinterpret_cast<float*>(Cout)[idx] = acc[m][n][r] + bv;
            }
        }
}

// ---------------------------------------------------------------------------
// Flash attention v3: swapped QK^T on 32x32x16 MFMA, in-register softmax.
// Block = (b, h, 128 q-rows), 4 waves x 32 q-rows. KV tile = 64 keys in LDS.
// mfma(K, Q): D[key][q], q = lane&31 -> P is lane-local, no P_lds.
// The lane->k-slot permutation of PV's A operand is absorbed into V's LDS
// store layout (key-group slot order [0,2,1,3] per 16-key block), so
// A1=[pk0..pk3], A2=[pk4..pk7] feed PV directly (zero cross-lane ops).
// 32x32x16 layouts (m74/m101 + 16x16 analogy): A row=lane&31, k=(lane>>5)*8+i;
// B col=lane&31, same k; D col=lane&31, row=(reg&3)+8*(reg>>2)+4*(lane>>5).
// No running max (scores bounded; validated R1-R3). Log2-domain softmax.
// ---------------------------------------------------------------------------
#define LDK 40
#define LDV 72

__global__ __launch_bounds__(256) void attn_mfma3(const ushort* __restrict__ qkv,
                                                  const ushort* __restrict__ vT,
                                                  ushort* __restrict__ ctx) {
    __shared__ __align__(16) ushort Ks[64 * LDK];
    __shared__ __align__(16) ushort Vs[64 * LDV];
    __shared__ float lsw[4][32];

    const int tid = threadIdx.x;
    const int w = tid >> 6, l = tid & 63;
    const int lq = l & 31;
    const int hi = l >> 5;
    const int h = blockIdx.y, b = blockIdx.z;
    const int i0 = blockIdx.x * 128;
    const int i0w = i0 + w * 32;
    const int g = h & 3;

    const float slope = exp2f(-0.5f * (float)(h + 1));
    const float k1 = 0.17677669529663687f * 1.4426950408889634f;  // scale*log2e
    const float k2 = slope * k1;
    const int Wint = (int)(275.0f / slope);

    // Q fragments: B-operand, lane (q=lq, hi) holds Q[q][hi*8+i] (+16 for qb)
    const ushort* qrow = qkv + ((size_t)(b * T_SEQ + i0w + lq)) * QKV_LD + h * 32 + hi * 8;
    const bf16x8 qa = *reinterpret_cast<const bf16x8*>(qrow);
    const bf16x8 qb = *reinterpret_cast<const bf16x8*>(qrow + 16);

    // staging mappings
    const int sd = tid >> 2;          // key row (K) / d row (V), 0..63
    const int c4 = tid & 3;
    const int sc8 = c4 * 8;
    const int voff = (c4 & 1) * 4 + (c4 >> 1) * 16;  // permuted V slot (ushorts)
    const ushort* kgp = qkv + (size_t)b * T_SEQ * QKV_LD + KOFF + g * 32 + (size_t)sd * QKV_LD + sc8;
    const ushort* vgp = vT + ((size_t)b * 256 + g * 64 + sd) * T_SEQ;

    int jt0 = i0 - Wint;
    if (jt0 < 0) jt0 = 0;
    jt0 &= ~63;
    const int jtend = i0 + 128;
    const int jwlo = i0w - Wint - 63;   // wave-level window skip

    f32x16 o0, o1;
#pragma unroll
    for (int r = 0; r < 16; ++r) { o0[r] = 0.0f; o1[r] = 0.0f; }
    float ls = 0.0f;

    uint4 kreg = *reinterpret_cast<const uint4*>(kgp + (size_t)jt0 * QKV_LD);
    uint4 vr0 = *reinterpret_cast<const uint4*>(vgp + jt0 + sc8);
    uint4 vr1 = *reinterpret_cast<const uint4*>(vgp + jt0 + 32 + sc8);

    for (int jt = jt0; jt < jtend; jt += 64) {
        __syncthreads();
        *reinterpret_cast<uint4*>(&Ks[sd * LDK + sc8]) = kreg;
        {   // permuted V stores: group g -> slot (g&~3)|((g&1)<<1)|((g>>1)&1)
            uint2 lo0 = make_uint2(vr0.x, vr0.y), hi0v = make_uint2(vr0.z, vr0.w);
            uint2 lo1 = make_uint2(vr1.x, vr1.y), hi1v = make_uint2(vr1.z, vr1.w);
            *reinterpret_cast<uint2*>(&Vs[sd * LDV + voff]) = lo0;
            *reinterpret_cast<uint2*>(&Vs[sd * LDV + voff + 8]) = hi0v;
            *reinterpret_cast<uint2*>(&Vs[sd * LDV + 32 + voff]) = lo1;
            *reinterpret_cast<uint2*>(&Vs[sd * LDV + 32 + voff + 8]) = hi1v;
        }
        __syncthreads();
        const int jn = jt + 64;
        if (jn < jtend) {
            kreg = *reinterpret_cast<const uint4*>(kgp + (size_t)jn * QKV_LD);
            vr0 = *reinterpret_cast<const uint4*>(vgp + jn + sc8);
            vr1 = *reinterpret_cast<const uint4*>(vgp + jn + 32 + sc8);
        }
        if (jt <= i0w + 31 && jt + 63 >= jwlo) {
#pragma unroll
            for (int s = 0; s < 2; ++s) {
                const int jts = jt + 32 * s;
                if (jts <= i0w + 31) {
                    const bf16x8 ka = *reinterpret_cast<const bf16x8*>(&Ks[(32 * s + lq) * LDK + hi * 8]);
                    const bf16x8 kb2 = *reinterpret_cast<const bf16x8*>(&Ks[(32 * s + lq) * LDK + 16 + hi * 8]);
                    f32x16 p;
#pragma unroll
                    for (int r = 0; r < 16; ++r) p[r] = 0.0f;
                    p = mfma32(ka, qa, p);
                    p = mfma32(kb2, qb, p);

                    const int dlt = jts + 4 * hi - i0w - lq;   // j - i at reg offset 0
                    const float base2 = k2 * (float)dlt;
                    const bool diag = (jts + 31 > i0w);
                    float pe[16];
#pragma unroll
                    for (int r = 0; r < 16; ++r) {
                        const int off = (r & 3) + 8 * (r >> 2);
                        const float arg = fmaf(p[r], k1, fmaf((float)off, k2, base2));
                        float e = exp2f(arg);
                        if (diag && (dlt + off > 0)) e = 0.0f;
                        ls += e;
                        pe[r] = e;
                    }
                    union { unsigned u[4]; bf16x8 v; } A1, A2;
#pragma unroll
                    for (int j2 = 0; j2 < 4; ++j2) A1.u[j2] = pack2bf(pe[2 * j2], pe[2 * j2 + 1]);
#pragma unroll
                    for (int j2 = 0; j2 < 4; ++j2) A2.u[j2] = pack2bf(pe[8 + 2 * j2], pe[9 + 2 * j2]);

                    const int vr0i = lq * LDV + 32 * s;
                    const int vr1i = (32 + lq) * LDV + 32 * s;
                    const bf16x8 v00 = *reinterpret_cast<const bf16x8*>(&Vs[vr0i + hi * 8]);
                    const bf16x8 v01 = *reinterpret_cast<const bf16x8*>(&Vs[vr0i + 16 + hi * 8]);
                    const bf16x8 v10 = *reinterpret_cast<const bf16x8*>(&Vs[vr1i + hi * 8]);
                    const bf16x8 v11 = *reinterpret_cast<const bf16x8*>(&Vs[vr1i + 16 + hi * 8]);
                    o0 = mfma32(A1.v, v00, o0);
                    o0 = mfma32(A2.v, v01, o0);
                    o1 = mfma32(A1.v, v10, o1);
                    o1 = mfma32(A2.v, v11, o1);
                }
            }
        }
    }

    // combine lane halves (each lane summed half the keys for its q)
    const float lst = ls + __shfl_xor(ls, 32);
    if (hi == 0) lsw[w][lq] = 1.0f / lst;
    // same-wave LDS write->read: wave-internal ordering, no barrier needed
    float invq[16];
#pragma unroll
    for (int r = 0; r < 16; ++r) {
        const int qr = (r & 3) + 8 * (r >> 2) + 4 * hi;
        invq[r] = lsw[w][qr];
    }
#pragma unroll
    for (int r = 0; r < 16; ++r) {
        const int qr = (r & 3) + 8 * (r >> 2) + 4 * hi;
        const size_t row = (size_t)(b * T_SEQ + i0w + qr);
        ctx[row * 1024 + h * 64 + lq] = f2bf(o0[r] * invq[r]);
        ctx[row * 1024 + h * 64 + 32 + lq] = f2bf(o1[r] * invq[r]);
    }
}

// ---------------------------------------------------------------------------
extern "C" void kernel_launch(void* const* d_in, const int* in_sizes, int n_in,
                              void* d_out, int out_size, void* d_ws, size_t ws_size,
                              hipStream_t stream) {
    const float* x  = (const float*)d_in[0];
    const float* Wq = (const float*)d_in[1];
    const float* Wk = (const float*)d_in[2];
    const float* Wv = (const float*)d_in[3];
    const float* Wp = (const float*)d_in[4];
    const float* bp = (const float*)d_in[5];

    const int M = B_SZ * T_SEQ;  // 4096

    ushort* ws    = (ushort*)d_ws;
    ushort* xb    = ws;                   // 4096x1024
    ushort* Wqkvt = xb + 4194304;         // 896x1024 (rows: Wq^T | Wk^T | Wv^T)
    ushort* Wpt   = Wqkvt + 917504;       // 1024x1024
    ushort* qkv   = Wpt + 1048576;        // 4096x896
    ushort* vTb   = qkv + 3670016;        // 2x256x2048
    ushort* cbuf  = vTb + 1048576;        // 4096x1024

    convert_bf16<<<2048, 256, 0, stream>>>(x, xb);
    prep_weights<<<dim3(60, 32), 256, 0, stream>>>(Wq, Wk, Wv, Wp, Wqkvt, Wpt);

    gemm_bf16<true><<<dim3(7, 32), 256, 0, stream>>>(xb, Wqkvt, nullptr, qkv, M, 896, 1024);

    transpose_bf16_str<<<dim3(8, 64, 2), 256, 0, stream>>>(
        qkv + VOFF, QKV_LD, (size_t)T_SEQ * QKV_LD, vTb, T_SEQ, 256, (size_t)256 * T_SEQ);

    attn_mfma3<<<dim3(T_SEQ / 128, H_CNT, B_SZ), 256, 0, stream>>>(qkv, vTb, cbuf);

    gemm_bf16<false><<<dim3(8, 32), 256, 0, stream>>>(cbuf, Wpt, bp, (float*)d_out, M, 1024, 1024);
}

// Round 6
// 126.433 us; speedup vs baseline: 27.0572x; 1.0421x over previous
//
#include <hip/hip_runtime.h>
#include <hip/hip_bf16.h>

#define T_SEQ 2048
#define H_CNT 16
#define B_SZ  2
#define QKV_LD 896
#define KOFF   512
#define VOFF   640

typedef float  f32x4   __attribute__((ext_vector_type(4)));
typedef float  f32x16  __attribute__((ext_vector_type(16)));
typedef __bf16 bf16x8  __attribute__((ext_vector_type(8)));

static __device__ __forceinline__ ushort f2bf(float f) {
    union { float f; unsigned u; } v; v.f = f;
    unsigned u = v.u;
    unsigned r = (u + 0x7fffu + ((u >> 16) & 1u)) >> 16;
    return (ushort)r;
}
static __device__ __forceinline__ unsigned pack2bf(float a, float b) {
    union { __bf16 h[2]; unsigned u; } pk;
    pk.h[0] = (__bf16)a; pk.h[1] = (__bf16)b;
    return pk.u;
}

static __device__ __forceinline__ f32x4 mfma16(bf16x8 a, bf16x8 b, f32x4 c) {
    return __builtin_amdgcn_mfma_f32_16x16x32_bf16(a, b, c, 0, 0, 0);
}
static __device__ __forceinline__ f32x16 mfma32(bf16x8 a, bf16x8 b, f32x16 c) {
    return __builtin_amdgcn_mfma_f32_32x32x16_bf16(a, b, c, 0, 0, 0);
}

// ---------------------------------------------------------------------------
// Elementwise fp32 -> bf16 convert (8 elems/thread)
// ---------------------------------------------------------------------------
__global__ __launch_bounds__(256) void convert_bf16(const float* __restrict__ src,
                                                    ushort* __restrict__ dst) {
    const int i = blockIdx.x * 256 + threadIdx.x;
    const float4 v0 = reinterpret_cast<const float4*>(src)[i * 2];
    const float4 v1 = reinterpret_cast<const float4*>(src)[i * 2 + 1];
    uint4 o;
    o.x = (unsigned)f2bf(v0.x) | ((unsigned)f2bf(v0.y) << 16);
    o.y = (unsigned)f2bf(v0.z) | ((unsigned)f2bf(v0.w) << 16);
    o.z = (unsigned)f2bf(v1.x) | ((unsigned)f2bf(v1.y) << 16);
    o.w = (unsigned)f2bf(v1.z) | ((unsigned)f2bf(v1.w) << 16);
    reinterpret_cast<uint4*>(dst)[i] = o;
}

// ---------------------------------------------------------------------------
// All 4 weight transposes merged: fp32 [1024][C] -> bf16 [C][1024].
// grid (60, 32): x<16 Wq, <20 Wk, <28 Wv, else Wp.
// ---------------------------------------------------------------------------
__global__ __launch_bounds__(256) void prep_weights(const float* __restrict__ Wq,
                                                    const float* __restrict__ Wk,
                                                    const float* __restrict__ Wv,
                                                    const float* __restrict__ Wp,
                                                    ushort* __restrict__ Wqkvt,
                                                    ushort* __restrict__ Wpt) {
    __shared__ float tile[32][33];
    const int x = blockIdx.x;
    const float* src; ushort* dst; int C, cx;
    if (x < 16)      { src = Wq; dst = Wqkvt;              C = 512;  cx = x; }
    else if (x < 20) { src = Wk; dst = Wqkvt + 512 * 1024; C = 128;  cx = x - 16; }
    else if (x < 28) { src = Wv; dst = Wqkvt + 640 * 1024; C = 256;  cx = x - 20; }
    else             { src = Wp; dst = Wpt;                C = 1024; cx = x - 28; }
    const int tx = threadIdx.x & 31, ty = threadIdx.x >> 5;
    const int r0 = blockIdx.y * 32, c0 = cx * 32;
#pragma unroll
    for (int i = 0; i < 32; i += 8)
        tile[ty + i][tx] = src[(size_t)(r0 + ty + i) * C + c0 + tx];
    __syncthreads();
#pragma unroll
    for (int i = 0; i < 32; i += 8)
        dst[(size_t)(c0 + ty + i) * 1024 + r0 + tx] = f2bf(tile[tx][ty + i]);
}

// ---------------------------------------------------------------------------
// bf16 strided transpose (for V): dst[z][c][r] = src[z*zoff + r*ld + c]
// ---------------------------------------------------------------------------
__global__ __launch_bounds__(256) void transpose_bf16_str(const ushort* __restrict__ src,
                                                          int src_ld, size_t src_zoff,
                                                          ushort* __restrict__ dst,
                                                          int R, int C, size_t dst_zoff) {
    __shared__ ushort tile[32][33];
    const int tx = threadIdx.x & 31, ty = threadIdx.x >> 5;
    const int r0 = blockIdx.y * 32, c0 = blockIdx.x * 32;
    const ushort* s = src + (size_t)blockIdx.z * src_zoff;
    ushort* d = dst + (size_t)blockIdx.z * dst_zoff;
#pragma unroll
    for (int i = 0; i < 32; i += 8)
        tile[ty + i][tx] = s[(size_t)(r0 + ty + i) * src_ld + c0 + tx];
    __syncthreads();
#pragma unroll
    for (int i = 0; i < 32; i += 8)
        d[(size_t)(c0 + ty + i) * R + r0 + tx] = tile[tx][ty + i];
}

// ---------------------------------------------------------------------------
// bf16 MFMA GEMM with register prefetch: C[M,N] = A[M,K] @ Bt[N,K]^T (+bias).
// 128x128 tile, BK=32, 4 waves (2x2), each wave 64x64 via 4x4 frags of 16x16x32.
// ---------------------------------------------------------------------------
template <bool OUT_BF16>
__global__ __launch_bounds__(256) void gemm_bf16(const ushort* __restrict__ A,
                                                 const ushort* __restrict__ Bt,
                                                 const float* __restrict__ bias,
                                                 void* __restrict__ Cout,
                                                 int M, int N, int K) {
    constexpr int LDL = 40;
    __shared__ __align__(16) ushort As[128 * LDL];
    __shared__ __align__(16) ushort Bs[128 * LDL];

    const int tid = threadIdx.x;
    const int w = tid >> 6, l = tid & 63;
    const int bm = blockIdx.y * 128, bn = blockIdx.x * 128;
    const int wr = (w >> 1) * 64, wc = (w & 1) * 64;
    const int lr = l & 15, lk = (l >> 4) * 8;

    const int sr = tid >> 2;
    const int sc = (tid & 3) * 8;

    const ushort* Ap0 = A + (size_t)(bm + sr) * K + sc;
    const ushort* Ap1 = A + (size_t)(bm + 64 + sr) * K + sc;
    const ushort* Bp0 = Bt + (size_t)(bn + sr) * K + sc;
    const ushort* Bp1 = Bt + (size_t)(bn + 64 + sr) * K + sc;

    f32x4 acc[4][4];
#pragma unroll
    for (int m = 0; m < 4; ++m)
#pragma unroll
        for (int n = 0; n < 4; ++n) acc[m][n] = (f32x4){0.f, 0.f, 0.f, 0.f};

    uint4 a0 = *reinterpret_cast<const uint4*>(Ap0);
    uint4 a1 = *reinterpret_cast<const uint4*>(Ap1);
    uint4 b0 = *reinterpret_cast<const uint4*>(Bp0);
    uint4 b1 = *reinterpret_cast<const uint4*>(Bp1);

    for (int k0 = 0; k0 < K; k0 += 32) {
        if (k0) __syncthreads();
        *reinterpret_cast<uint4*>(&As[sr * LDL + sc]) = a0;
        *reinterpret_cast<uint4*>(&As[(64 + sr) * LDL + sc]) = a1;
        *reinterpret_cast<uint4*>(&Bs[sr * LDL + sc]) = b0;
        *reinterpret_cast<uint4*>(&Bs[(64 + sr) * LDL + sc]) = b1;
        __syncthreads();
        if (k0 + 32 < K) {
            a0 = *reinterpret_cast<const uint4*>(Ap0 + k0 + 32);
            a1 = *reinterpret_cast<const uint4*>(Ap1 + k0 + 32);
            b0 = *reinterpret_cast<const uint4*>(Bp0 + k0 + 32);
            b1 = *reinterpret_cast<const uint4*>(Bp1 + k0 + 32);
        }
        bf16x8 af[4], bfr[4];
#pragma unroll
        for (int m = 0; m < 4; ++m)
            af[m] = *reinterpret_cast<const bf16x8*>(&As[(wr + m * 16 + lr) * LDL + lk]);
#pragma unroll
        for (int n = 0; n < 4; ++n)
            bfr[n] = *reinterpret_cast<const bf16x8*>(&Bs[(wc + n * 16 + lr) * LDL + lk]);
#pragma unroll
        for (int m = 0; m < 4; ++m)
#pragma unroll
            for (int n = 0; n < 4; ++n)
                acc[m][n] = mfma16(af[m], bfr[n], acc[m][n]);
    }

    const int orow = bm + wr + (l >> 4) * 4;
    const int ocol0 = bn + wc + lr;
#pragma unroll
    for (int m = 0; m < 4; ++m)
#pragma unroll
        for (int n = 0; n < 4; ++n) {
            const int col = ocol0 + n * 16;
            const float bv = OUT_BF16 ? 0.0f : bias[col];
#pragma unroll
            for (int r = 0; r < 4; ++r) {
                const size_t idx = (size_t)(orow + m * 16 + r) * N + col;
                if constexpr (OUT_BF16)
                    reinterpret_cast<ushort*>(Cout)[idx] = f2bf(acc[m][n][r]);
                else
                    reinterpret_cast<float*>(Cout)[idx] = acc[m][n][r] + bv;
            }
        }
}

// ---------------------------------------------------------------------------
// Flash attention v5: R4's proven staging protocol + head-sharing.
// Block = (xq, group g, batch b); 4 waves = heads {g, g+4, g+8, g+12}, all on
// the SAME 32 q-rows from ONE shared K/V LDS stage (KV identical within a
// group: tile() semantics). ONE q-tile per block (no pairing -> 512 blocks,
// 2 waves/SIMD); balance via interleaved perm: xq -> tile (xq/2) or (63-xq/2),
// so consecutively-dispatched block pairs sum to ~uniform load.
// Epilogue is LDS-free (shfl broadcast). Prefetch conditional, no wrap.
// Inner compute identical to R4/R5-verified (swapped QK^T on 32x32x16,
// in-register softmax, permuted V slots absorb the lane->k-slot shuffle).
// ---------------------------------------------------------------------------
#define LDK 40
#define LDV 72

__global__ __launch_bounds__(256) void attn_mfma5(const ushort* __restrict__ qkv,
                                                  const ushort* __restrict__ vT,
                                                  ushort* __restrict__ ctx) {
    __shared__ __align__(16) ushort Ks[64 * LDK];
    __shared__ __align__(16) ushort Vs[64 * LDV];

    const int tid = threadIdx.x;
    const int w = tid >> 6, l = tid & 63;
    const int lq = l & 31;
    const int hi = l >> 5;
    const int xq = blockIdx.x, g = blockIdx.y, b = blockIdx.z;
    const int t = (xq & 1) ? (63 - (xq >> 1)) : (xq >> 1);
    const int i0 = t * 32;
    const int h = g + 4 * w;   // this wave's head (group = h & 3)

    const float slope = exp2f(-0.5f * (float)(h + 1));
    const float k1 = 0.17677669529663687f * 1.4426950408889634f;  // scale*log2e
    const float k2 = slope * k1;
    const int Wint = (int)(275.0f / slope);

    // Q fragments: B-operand, lane (q=lq, hi) holds Q[q][hi*8+i] (+16 for qb)
    const ushort* qrow = qkv + ((size_t)(b * T_SEQ + i0 + lq)) * QKV_LD + h * 32 + hi * 8;
    const bf16x8 qa = *reinterpret_cast<const bf16x8*>(qrow);
    const bf16x8 qb = *reinterpret_cast<const bf16x8*>(qrow + 16);

    // staging mappings (256 threads)
    const int sd = tid >> 2;          // key row (K) / d row (V), 0..63
    const int c4 = tid & 3;
    const int sc8 = c4 * 8;
    const int voff = (c4 & 1) * 4 + (c4 >> 1) * 16;  // permuted V slot (ushorts)
    const ushort* kgp = qkv + (size_t)b * T_SEQ * QKV_LD + KOFF + g * 32 + (size_t)sd * QKV_LD + sc8;
    const ushort* vgp = vT + ((size_t)b * 256 + g * 64 + sd) * T_SEQ;

    const int jtend = i0 + 32;
    const int jwlo = i0 - Wint - 63;   // wave-level window skip (conservative)

    f32x16 o0, o1;
#pragma unroll
    for (int r = 0; r < 16; ++r) { o0[r] = 0.0f; o1[r] = 0.0f; }
    float ls = 0.0f;

    // preload tile 0
    uint4 kreg = *reinterpret_cast<const uint4*>(kgp);
    uint4 vr0 = *reinterpret_cast<const uint4*>(vgp + sc8);
    uint4 vr1 = *reinterpret_cast<const uint4*>(vgp + 32 + sc8);

    for (int jt = 0; jt < jtend; jt += 64) {
        __syncthreads();
        *reinterpret_cast<uint4*>(&Ks[sd * LDK + sc8]) = kreg;
        {   // permuted V stores
            uint2 lo0 = make_uint2(vr0.x, vr0.y), hi0v = make_uint2(vr0.z, vr0.w);
            uint2 lo1 = make_uint2(vr1.x, vr1.y), hi1v = make_uint2(vr1.z, vr1.w);
            *reinterpret_cast<uint2*>(&Vs[sd * LDV + voff]) = lo0;
            *reinterpret_cast<uint2*>(&Vs[sd * LDV + voff + 8]) = hi0v;
            *reinterpret_cast<uint2*>(&Vs[sd * LDV + 32 + voff]) = lo1;
            *reinterpret_cast<uint2*>(&Vs[sd * LDV + 32 + voff + 8]) = hi1v;
        }
        __syncthreads();
        const int jn = jt + 64;
        if (jn < jtend) {   // conditional prefetch (no wrap)
            kreg = *reinterpret_cast<const uint4*>(kgp + (size_t)jn * QKV_LD);
            vr0 = *reinterpret_cast<const uint4*>(vgp + jn + sc8);
            vr1 = *reinterpret_cast<const uint4*>(vgp + jn + 32 + sc8);
        }
        if (jt + 63 >= jwlo) {
#pragma unroll
            for (int s = 0; s < 2; ++s) {
                const int jts = jt + 32 * s;
                if (jts <= i0 + 31) {
                    const bf16x8 ka = *reinterpret_cast<const bf16x8*>(&Ks[(32 * s + lq) * LDK + hi * 8]);
                    const bf16x8 kb2 = *reinterpret_cast<const bf16x8*>(&Ks[(32 * s + lq) * LDK + 16 + hi * 8]);
                    f32x16 p;
#pragma unroll
                    for (int r = 0; r < 16; ++r) p[r] = 0.0f;
                    p = mfma32(ka, qa, p);
                    p = mfma32(kb2, qb, p);

                    const int dlt = jts + 4 * hi - i0 - lq;   // j - i at reg offset 0
                    const float base2 = k2 * (float)dlt;
                    const bool diag = (jts + 31 > i0);
                    float pe[16];
#pragma unroll
                    for (int r = 0; r < 16; ++r) {
                        const int off = (r & 3) + 8 * (r >> 2);
                        const float arg = fmaf(p[r], k1, fmaf((float)off, k2, base2));
                        float e = exp2f(arg);
                        if (diag && (dlt + off > 0)) e = 0.0f;
                        ls += e;
                        pe[r] = e;
                    }
                    union { unsigned u[4]; bf16x8 v; } A1, A2;
#pragma unroll
                    for (int j2 = 0; j2 < 4; ++j2) A1.u[j2] = pack2bf(pe[2 * j2], pe[2 * j2 + 1]);
#pragma unroll
                    for (int j2 = 0; j2 < 4; ++j2) A2.u[j2] = pack2bf(pe[8 + 2 * j2], pe[9 + 2 * j2]);

                    const int vr0i = lq * LDV + 32 * s;
                    const int vr1i = (32 + lq) * LDV + 32 * s;
                    const bf16x8 v00 = *reinterpret_cast<const bf16x8*>(&Vs[vr0i + hi * 8]);
                    const bf16x8 v01 = *reinterpret_cast<const bf16x8*>(&Vs[vr0i + 16 + hi * 8]);
                    const bf16x8 v10 = *reinterpret_cast<const bf16x8*>(&Vs[vr1i + hi * 8]);
                    const bf16x8 v11 = *reinterpret_cast<const bf16x8*>(&Vs[vr1i + 16 + hi * 8]);
                    o0 = mfma32(A1.v, v00, o0);
                    o0 = mfma32(A2.v, v01, o0);
                    o1 = mfma32(A1.v, v10, o1);
                    o1 = mfma32(A2.v, v11, o1);
                }
            }
        }
    }

    // ---- LDS-free epilogue: shfl broadcast of 1/l ----
    const float inv = 1.0f / (ls + __shfl_xor(ls, 32));  // lane lq (both halves): 1/l for q=lq
#pragma unroll
    for (int r = 0; r < 16; ++r) {
        const int qr = (r & 3) + 8 * (r >> 2) + 4 * hi;
        const float invq = __shfl(inv, qr);   // source lane qr (half 0) holds q=qr
        const size_t row = (size_t)(b * T_SEQ + i0 + qr);
        ctx[row * 1024 + h * 64 + lq] = f2bf(o0[r] * invq);
        ctx[row * 1024 + h * 64 + 32 + lq] = f2bf(o1[r] * invq);
    }
}

// ---------------------------------------------------------------------------
extern "C" void kernel_launch(void* const* d_in, const int* in_sizes, int n_in,
                              void* d_out, int out_size, void* d_ws, size_t ws_size,
                              hipStream_t stream) {
    const float* x  = (const float*)d_in[0];
    const float* Wq = (const float*)d_in[1];
    const float* Wk = (const float*)d_in[2];
    const float* Wv = (const float*)d_in[3];
    const float* Wp = (const float*)d_in[4];
    const float* bp = (const float*)d_in[5];

    const int M = B_SZ * T_SEQ;  // 4096

    ushort* ws    = (ushort*)d_ws;
    ushort* xb    = ws;                   // 4096x1024
    ushort* Wqkvt = xb + 4194304;         // 896x1024 (rows: Wq^T | Wk^T | Wv^T)
    ushort* Wpt   = Wqkvt + 917504;       // 1024x1024
    ushort* qkv   = Wpt + 1048576;        // 4096x896
    ushort* vTb   = qkv + 3670016;        // 2x256x2048
    ushort* cbuf  = vTb + 1048576;        // 4096x1024

    convert_bf16<<<2048, 256, 0, stream>>>(x, xb);
    prep_weights<<<dim3(60, 32), 256, 0, stream>>>(Wq, Wk, Wv, Wp, Wqkvt, Wpt);

    gemm_bf16<true><<<dim3(7, 32), 256, 0, stream>>>(xb, Wqkvt, nullptr, qkv, M, 896, 1024);

    transpose_bf16_str<<<dim3(8, 64, 2), 256, 0, stream>>>(
        qkv + VOFF, QKV_LD, (size_t)T_SEQ * QKV_LD, vTb, T_SEQ, 256, (size_t)256 * T_SEQ);

    attn_mfma5<<<dim3(64, 4, B_SZ), 256, 0, stream>>>(qkv, vTb, cbuf);

    gemm_bf16<false><<<dim3(8, 32), 256, 0, stream>>>(cbuf, Wpt, bp, (float*)d_out, M, 1024, 1024);
}

// Round 7
// 109.600 us; speedup vs baseline: 31.2127x; 1.1536x over previous
//
#include <hip/hip_runtime.h>
#include <hip/hip_bf16.h>

#define T_SEQ 2048
#define H_CNT 16
#define B_SZ  2
#define QKV_LD 896
#define KOFF   512
#define VOFF   640

typedef float  f32x4   __attribute__((ext_vector_type(4)));
typedef float  f32x16  __attribute__((ext_vector_type(16)));
typedef __bf16 bf16x8  __attribute__((ext_vector_type(8)));

static __device__ __forceinline__ ushort f2bf(float f) {
    union { float f; unsigned u; } v; v.f = f;
    unsigned u = v.u;
    unsigned r = (u + 0x7fffu + ((u >> 16) & 1u)) >> 16;
    return (ushort)r;
}
static __device__ __forceinline__ unsigned pack2bf(float a, float b) {
    union { __bf16 h[2]; unsigned u; } pk;
    pk.h[0] = (__bf16)a; pk.h[1] = (__bf16)b;
    return pk.u;
}

static __device__ __forceinline__ f32x4 mfma16(bf16x8 a, bf16x8 b, f32x4 c) {
    return __builtin_amdgcn_mfma_f32_16x16x32_bf16(a, b, c, 0, 0, 0);
}
static __device__ __forceinline__ f32x16 mfma32(bf16x8 a, bf16x8 b, f32x16 c) {
    return __builtin_amdgcn_mfma_f32_32x32x16_bf16(a, b, c, 0, 0, 0);
}

// ---------------------------------------------------------------------------
// Elementwise fp32 -> bf16 convert (8 elems/thread)
// ---------------------------------------------------------------------------
__global__ __launch_bounds__(256) void convert_bf16(const float* __restrict__ src,
                                                    ushort* __restrict__ dst) {
    const int i = blockIdx.x * 256 + threadIdx.x;
    const float4 v0 = reinterpret_cast<const float4*>(src)[i * 2];
    const float4 v1 = reinterpret_cast<const float4*>(src)[i * 2 + 1];
    uint4 o;
    o.x = (unsigned)f2bf(v0.x) | ((unsigned)f2bf(v0.y) << 16);
    o.y = (unsigned)f2bf(v0.z) | ((unsigned)f2bf(v0.w) << 16);
    o.z = (unsigned)f2bf(v1.x) | ((unsigned)f2bf(v1.y) << 16);
    o.w = (unsigned)f2bf(v1.z) | ((unsigned)f2bf(v1.w) << 16);
    reinterpret_cast<uint4*>(dst)[i] = o;
}

// ---------------------------------------------------------------------------
// All 4 weight transposes merged: fp32 [1024][C] -> bf16 [C][1024].
// grid (60, 32): x<16 Wq, <20 Wk, <28 Wv, else Wp.
// ---------------------------------------------------------------------------
__global__ __launch_bounds__(256) void prep_weights(const float* __restrict__ Wq,
                                                    const float* __restrict__ Wk,
                                                    const float* __restrict__ Wv,
                                                    const float* __restrict__ Wp,
                                                    ushort* __restrict__ Wqkvt,
                                                    ushort* __restrict__ Wpt) {
    __shared__ float tile[32][33];
    const int x = blockIdx.x;
    const float* src; ushort* dst; int C, cx;
    if (x < 16)      { src = Wq; dst = Wqkvt;              C = 512;  cx = x; }
    else if (x < 20) { src = Wk; dst = Wqkvt + 512 * 1024; C = 128;  cx = x - 16; }
    else if (x < 28) { src = Wv; dst = Wqkvt + 640 * 1024; C = 256;  cx = x - 20; }
    else             { src = Wp; dst = Wpt;                C = 1024; cx = x - 28; }
    const int tx = threadIdx.x & 31, ty = threadIdx.x >> 5;
    const int r0 = blockIdx.y * 32, c0 = cx * 32;
#pragma unroll
    for (int i = 0; i < 32; i += 8)
        tile[ty + i][tx] = src[(size_t)(r0 + ty + i) * C + c0 + tx];
    __syncthreads();
#pragma unroll
    for (int i = 0; i < 32; i += 8)
        dst[(size_t)(c0 + ty + i) * 1024 + r0 + tx] = f2bf(tile[tx][ty + i]);
}

// ---------------------------------------------------------------------------
// bf16 strided transpose (for V): dst[z][c][r] = src[z*zoff + r*ld + c]
// ---------------------------------------------------------------------------
__global__ __launch_bounds__(256) void transpose_bf16_str(const ushort* __restrict__ src,
                                                          int src_ld, size_t src_zoff,
                                                          ushort* __restrict__ dst,
                                                          int R, int C, size_t dst_zoff) {
    __shared__ ushort tile[32][33];
    const int tx = threadIdx.x & 31, ty = threadIdx.x >> 5;
    const int r0 = blockIdx.y * 32, c0 = blockIdx.x * 32;
    const ushort* s = src + (size_t)blockIdx.z * src_zoff;
    ushort* d = dst + (size_t)blockIdx.z * dst_zoff;
#pragma unroll
    for (int i = 0; i < 32; i += 8)
        tile[ty + i][tx] = s[(size_t)(r0 + ty + i) * src_ld + c0 + tx];
    __syncthreads();
#pragma unroll
    for (int i = 0; i < 32; i += 8)
        d[(size_t)(c0 + ty + i) * R + r0 + tx] = tile[tx][ty + i];
}

// ---------------------------------------------------------------------------
// bf16 MFMA GEMM with register prefetch: C[M,N] = A[M,K] @ Bt[N,K]^T (+bias).
// 128x128 tile, BK=32, 4 waves (2x2), each wave 64x64 via 4x4 frags of 16x16x32.
// ---------------------------------------------------------------------------
template <bool OUT_BF16>
__global__ __launch_bounds__(256) void gemm_bf16(const ushort* __restrict__ A,
                                                 const ushort* __restrict__ Bt,
                                                 const float* __restrict__ bias,
                                                 void* __restrict__ Cout,
                                                 int M, int N, int K) {
    constexpr int LDL = 40;
    __shared__ __align__(16) ushort As[128 * LDL];
    __shared__ __align__(16) ushort Bs[128 * LDL];

    const int tid = threadIdx.x;
    const int w = tid >> 6, l = tid & 63;
    const int bm = blockIdx.y * 128, bn = blockIdx.x * 128;
    const int wr = (w >> 1) * 64, wc = (w & 1) * 64;
    const int lr = l & 15, lk = (l >> 4) * 8;

    const int sr = tid >> 2;
    const int sc = (tid & 3) * 8;

    const ushort* Ap0 = A + (size_t)(bm + sr) * K + sc;
    const ushort* Ap1 = A + (size_t)(bm + 64 + sr) * K + sc;
    const ushort* Bp0 = Bt + (size_t)(bn + sr) * K + sc;
    const ushort* Bp1 = Bt + (size_t)(bn + 64 + sr) * K + sc;

    f32x4 acc[4][4];
#pragma unroll
    for (int m = 0; m < 4; ++m)
#pragma unroll
        for (int n = 0; n < 4; ++n) acc[m][n] = (f32x4){0.f, 0.f, 0.f, 0.f};

    uint4 a0 = *reinterpret_cast<const uint4*>(Ap0);
    uint4 a1 = *reinterpret_cast<const uint4*>(Ap1);
    uint4 b0 = *reinterpret_cast<const uint4*>(Bp0);
    uint4 b1 = *reinterpret_cast<const uint4*>(Bp1);

    for (int k0 = 0; k0 < K; k0 += 32) {
        if (k0) __syncthreads();
        *reinterpret_cast<uint4*>(&As[sr * LDL + sc]) = a0;
        *reinterpret_cast<uint4*>(&As[(64 + sr) * LDL + sc]) = a1;
        *reinterpret_cast<uint4*>(&Bs[sr * LDL + sc]) = b0;
        *reinterpret_cast<uint4*>(&Bs[(64 + sr) * LDL + sc]) = b1;
        __syncthreads();
        if (k0 + 32 < K) {
            a0 = *reinterpret_cast<const uint4*>(Ap0 + k0 + 32);
            a1 = *reinterpret_cast<const uint4*>(Ap1 + k0 + 32);
            b0 = *reinterpret_cast<const uint4*>(Bp0 + k0 + 32);
            b1 = *reinterpret_cast<const uint4*>(Bp1 + k0 + 32);
        }
        bf16x8 af[4], bfr[4];
#pragma unroll
        for (int m = 0; m < 4; ++m)
            af[m] = *reinterpret_cast<const bf16x8*>(&As[(wr + m * 16 + lr) * LDL + lk]);
#pragma unroll
        for (int n = 0; n < 4; ++n)
            bfr[n] = *reinterpret_cast<const bf16x8*>(&Bs[(wc + n * 16 + lr) * LDL + lk]);
#pragma unroll
        for (int m = 0; m < 4; ++m)
#pragma unroll
            for (int n = 0; n < 4; ++n)
                acc[m][n] = mfma16(af[m], bfr[n], acc[m][n]);
    }

    const int orow = bm + wr + (l >> 4) * 4;
    const int ocol0 = bn + wc + lr;
#pragma unroll
    for (int m = 0; m < 4; ++m)
#pragma unroll
        for (int n = 0; n < 4; ++n) {
            const int col = ocol0 + n * 16;
            const float bv = OUT_BF16 ? 0.0f : bias[col];
#pragma unroll
            for (int r = 0; r < 4; ++r) {
                const size_t idx = (size_t)(orow + m * 16 + r) * N + col;
                if constexpr (OUT_BF16)
                    reinterpret_cast<ushort*>(Cout)[idx] = f2bf(acc[m][n][r]);
                else
                    reinterpret_cast<float*>(Cout)[idx] = acc[m][n][r] + bv;
            }
        }
}

// ---------------------------------------------------------------------------
// Flash attention v6: uniform 8-wave blocks + 1-barrier double-buffer.
// Block = (tp, group g, batch b), 512 threads. Waves 0-3 = heads {g,g+4,g+8,
// g+12} on q-tile tp; waves 4-7 = same heads on q-tile 63-tp. One shared
// K/V stage (double-buffered) serves all 8 waves; every block runs the SAME
// number of staging iterations -> perfect balance under any dispatch map.
// Protocol per tile: {ds_write buf[cur]; issue loads t+1; barrier;
// compute buf[cur]}. Safety: writes to buf[x] at iter i+2 occur only after
// all waves passed barrier(i+1), which is after all iter-i reads of buf[x].
// Staging roles: tid<256 stages K (1x uint4), tid>=256 stages V (2x uint4,
// permuted slots - R4-verified layout absorbing the lane->k-slot shuffle).
// Inner compute/masks/epilogue identical to R6-verified attn_mfma5.
// ---------------------------------------------------------------------------
#define LDK 40
#define LDV 72

__global__ __launch_bounds__(512) void attn_mfma6(const ushort* __restrict__ qkv,
                                                  const ushort* __restrict__ vT,
                                                  ushort* __restrict__ ctx) {
    __shared__ __align__(16) ushort Ks[2][64 * LDK];
    __shared__ __align__(16) ushort Vs[2][64 * LDV];

    const int tid = threadIdx.x;
    const int w = tid >> 6, l = tid & 63;
    const int lq = l & 31;
    const int hi = l >> 5;
    const int tp = blockIdx.x, g = blockIdx.y, b = blockIdx.z;
    const int t = (w < 4) ? tp : (63 - tp);
    const int i0 = t * 32;
    const int h = g + 4 * (w & 3);   // this wave's head (group = h & 3)

    const float slope = exp2f(-0.5f * (float)(h + 1));
    const float k1 = 0.17677669529663687f * 1.4426950408889634f;  // scale*log2e
    const float k2 = slope * k1;
    const int Wint = (int)(275.0f / slope);

    // Q fragments: B-operand, lane (q=lq, hi) holds Q[q][hi*8+i] (+16 for qb)
    const ushort* qrow = qkv + ((size_t)(b * T_SEQ + i0 + lq)) * QKV_LD + h * 32 + hi * 8;
    const bf16x8 qa = *reinterpret_cast<const bf16x8*>(qrow);
    const bf16x8 qb = *reinterpret_cast<const bf16x8*>(qrow + 16);

    // staging role split: tid<256 -> K, tid>=256 -> V
    const int st = tid & 255;
    const int sd = st >> 2;           // key row (K) / d row (V), 0..63
    const int c4 = st & 3;
    const int sc8 = c4 * 8;
    const int voff = (c4 & 1) * 4 + (c4 >> 1) * 16;  // permuted V slot (ushorts)
    const ushort* kgp = qkv + (size_t)b * T_SEQ * QKV_LD + KOFF + g * 32 + (size_t)sd * QKV_LD + sc8;
    const ushort* vgp = vT + ((size_t)b * 256 + g * 64 + sd) * T_SEQ;

    const int jtend = i0 + 32;                    // this wave's causal end
    const int jtend_max = (64 - tp) * 32;         // block-uniform staging bound
    const int jwlo = i0 - Wint - 63;              // wave-level window skip

    f32x16 o0, o1;
#pragma unroll
    for (int r = 0; r < 16; ++r) { o0[r] = 0.0f; o1[r] = 0.0f; }
    float ls = 0.0f;

    // prologue: load tile 0 into regs (role-dependent)
    uint4 kreg, vr0, vr1;
    if (tid < 256) {
        kreg = *reinterpret_cast<const uint4*>(kgp);
    } else {
        vr0 = *reinterpret_cast<const uint4*>(vgp + sc8);
        vr1 = *reinterpret_cast<const uint4*>(vgp + 32 + sc8);
    }

    int cur = 0;
    for (int jt = 0; jt < jtend_max; jt += 64) {
        // ---- stage buf[cur] from regs (all waves past previous barrier) ----
        if (tid < 256) {
            *reinterpret_cast<uint4*>(&Ks[cur][sd * LDK + sc8]) = kreg;
        } else {
            uint2 lo0 = make_uint2(vr0.x, vr0.y), hi0v = make_uint2(vr0.z, vr0.w);
            uint2 lo1 = make_uint2(vr1.x, vr1.y), hi1v = make_uint2(vr1.z, vr1.w);
            *reinterpret_cast<uint2*>(&Vs[cur][sd * LDV + voff]) = lo0;
            *reinterpret_cast<uint2*>(&Vs[cur][sd * LDV + voff + 8]) = hi0v;
            *reinterpret_cast<uint2*>(&Vs[cur][sd * LDV + 32 + voff]) = lo1;
            *reinterpret_cast<uint2*>(&Vs[cur][sd * LDV + 32 + voff + 8]) = hi1v;
        }
        // ---- issue next-tile loads (hidden under compute + barrier) ----
        const int jn = jt + 64;
        if (jn < jtend_max) {
            if (tid < 256) {
                kreg = *reinterpret_cast<const uint4*>(kgp + (size_t)jn * QKV_LD);
            } else {
                vr0 = *reinterpret_cast<const uint4*>(vgp + jn + sc8);
                vr1 = *reinterpret_cast<const uint4*>(vgp + jn + 32 + sc8);
            }
        }
        __syncthreads();   // buf[cur] ready

        if (jt < jtend && jt + 63 >= jwlo) {
#pragma unroll
            for (int s = 0; s < 2; ++s) {
                const int jts = jt + 32 * s;
                if (jts <= i0 + 31) {
                    const bf16x8 ka = *reinterpret_cast<const bf16x8*>(&Ks[cur][(32 * s + lq) * LDK + hi * 8]);
                    const bf16x8 kb2 = *reinterpret_cast<const bf16x8*>(&Ks[cur][(32 * s + lq) * LDK + 16 + hi * 8]);
                    f32x16 p;
#pragma unroll
                    for (int r = 0; r < 16; ++r) p[r] = 0.0f;
                    __builtin_amdgcn_s_setprio(1);
                    p = mfma32(ka, qa, p);
                    p = mfma32(kb2, qb, p);
                    __builtin_amdgcn_s_setprio(0);

                    const int dlt = jts + 4 * hi - i0 - lq;   // j - i at reg offset 0
                    const float base2 = k2 * (float)dlt;
                    const bool diag = (jts + 31 > i0);
                    float pe[16];
#pragma unroll
                    for (int r = 0; r < 16; ++r) {
                        const int off = (r & 3) + 8 * (r >> 2);
                        const float arg = fmaf(p[r], k1, fmaf((float)off, k2, base2));
                        float e = exp2f(arg);
                        if (diag && (dlt + off > 0)) e = 0.0f;
                        ls += e;
                        pe[r] = e;
                    }
                    union { unsigned u[4]; bf16x8 v; } A1, A2;
#pragma unroll
                    for (int j2 = 0; j2 < 4; ++j2) A1.u[j2] = pack2bf(pe[2 * j2], pe[2 * j2 + 1]);
#pragma unroll
                    for (int j2 = 0; j2 < 4; ++j2) A2.u[j2] = pack2bf(pe[8 + 2 * j2], pe[9 + 2 * j2]);

                    const int vr0i = lq * LDV + 32 * s;
                    const int vr1i = (32 + lq) * LDV + 32 * s;
                    const bf16x8 v00 = *reinterpret_cast<const bf16x8*>(&Vs[cur][vr0i + hi * 8]);
                    const bf16x8 v01 = *reinterpret_cast<const bf16x8*>(&Vs[cur][vr0i + 16 + hi * 8]);
                    const bf16x8 v10 = *reinterpret_cast<const bf16x8*>(&Vs[cur][vr1i + hi * 8]);
                    const bf16x8 v11 = *reinterpret_cast<const bf16x8*>(&Vs[cur][vr1i + 16 + hi * 8]);
                    __builtin_amdgcn_s_setprio(1);
                    o0 = mfma32(A1.v, v00, o0);
                    o0 = mfma32(A2.v, v01, o0);
                    o1 = mfma32(A1.v, v10, o1);
                    o1 = mfma32(A2.v, v11, o1);
                    __builtin_amdgcn_s_setprio(0);
                }
            }
        }
        cur ^= 1;
    }

    // ---- LDS-free epilogue: shfl broadcast of 1/l ----
    const float inv = 1.0f / (ls + __shfl_xor(ls, 32));
#pragma unroll
    for (int r = 0; r < 16; ++r) {
        const int qr = (r & 3) + 8 * (r >> 2) + 4 * hi;
        const float invq = __shfl(inv, qr);   // source lane qr (half 0) holds q=qr
        const size_t row = (size_t)(b * T_SEQ + i0 + qr);
        ctx[row * 1024 + h * 64 + lq] = f2bf(o0[r] * invq);
        ctx[row * 1024 + h * 64 + 32 + lq] = f2bf(o1[r] * invq);
    }
}

// ---------------------------------------------------------------------------
extern "C" void kernel_launch(void* const* d_in, const int* in_sizes, int n_in,
                              void* d_out, int out_size, void* d_ws, size_t ws_size,
                              hipStream_t stream) {
    const float* x  = (const float*)d_in[0];
    const float* Wq = (const float*)d_in[1];
    const float* Wk = (const float*)d_in[2];
    const float* Wv = (const float*)d_in[3];
    const float* Wp = (const float*)d_in[4];
    const float* bp = (const float*)d_in[5];

    const int M = B_SZ * T_SEQ;  // 4096

    ushort* ws    = (ushort*)d_ws;
    ushort* xb    = ws;                   // 4096x1024
    ushort* Wqkvt = xb + 4194304;         // 896x1024 (rows: Wq^T | Wk^T | Wv^T)
    ushort* Wpt   = Wqkvt + 917504;       // 1024x1024
    ushort* qkv   = Wpt + 1048576;        // 4096x896
    ushort* vTb   = qkv + 3670016;        // 2x256x2048
    ushort* cbuf  = vTb + 1048576;        // 4096x1024

    convert_bf16<<<2048, 256, 0, stream>>>(x, xb);
    prep_weights<<<dim3(60, 32), 256, 0, stream>>>(Wq, Wk, Wv, Wp, Wqkvt, Wpt);

    gemm_bf16<true><<<dim3(7, 32), 256, 0, stream>>>(xb, Wqkvt, nullptr, qkv, M, 896, 1024);

    transpose_bf16_str<<<dim3(8, 64, 2), 256, 0, stream>>>(
        qkv + VOFF, QKV_LD, (size_t)T_SEQ * QKV_LD, vTb, T_SEQ, 256, (size_t)256 * T_SEQ);

    attn_mfma6<<<dim3(32, 4, B_SZ), 512, 0, stream>>>(qkv, vTb, cbuf);

    gemm_bf16<false><<<dim3(8, 32), 256, 0, stream>>>(cbuf, Wpt, bp, (float*)d_out, M, 1024, 1024);
}

// Round 8
// 100.502 us; speedup vs baseline: 34.0383x; 1.0905x over previous
//
#include <hip/hip_runtime.h>
#include <hip/hip_bf16.h>

#define T_SEQ 2048
#define H_CNT 16
#define B_SZ  2
#define QKV_LD 896
#define KOFF   512
#define VOFF   640

typedef float  f32x4   __attribute__((ext_vector_type(4)));
typedef float  f32x16  __attribute__((ext_vector_type(16)));
typedef __bf16 bf16x8  __attribute__((ext_vector_type(8)));

static __device__ __forceinline__ ushort f2bf(float f) {
    union { float f; unsigned u; } v; v.f = f;
    unsigned u = v.u;
    unsigned r = (u + 0x7fffu + ((u >> 16) & 1u)) >> 16;
    return (ushort)r;
}
static __device__ __forceinline__ unsigned pack2bf(float a, float b) {
    union { __bf16 h[2]; unsigned u; } pk;
    pk.h[0] = (__bf16)a; pk.h[1] = (__bf16)b;
    return pk.u;
}

static __device__ __forceinline__ f32x4 mfma16(bf16x8 a, bf16x8 b, f32x4 c) {
    return __builtin_amdgcn_mfma_f32_16x16x32_bf16(a, b, c, 0, 0, 0);
}
static __device__ __forceinline__ f32x16 mfma32(bf16x8 a, bf16x8 b, f32x16 c) {
    return __builtin_amdgcn_mfma_f32_32x32x16_bf16(a, b, c, 0, 0, 0);
}

// async global->LDS, 16B per lane; LDS dest is wave-uniform base + lane*16
static __device__ __forceinline__ void gl_lds16(const void* g, void* l) {
    __builtin_amdgcn_global_load_lds((const __attribute__((address_space(1))) void*)g,
                                     (__attribute__((address_space(3))) void*)l, 16, 0, 0);
}

// ---------------------------------------------------------------------------
// Elementwise fp32 -> bf16 convert (8 elems/thread)
// ---------------------------------------------------------------------------
__global__ __launch_bounds__(256) void convert_bf16(const float* __restrict__ src,
                                                    ushort* __restrict__ dst) {
    const int i = blockIdx.x * 256 + threadIdx.x;
    const float4 v0 = reinterpret_cast<const float4*>(src)[i * 2];
    const float4 v1 = reinterpret_cast<const float4*>(src)[i * 2 + 1];
    uint4 o;
    o.x = (unsigned)f2bf(v0.x) | ((unsigned)f2bf(v0.y) << 16);
    o.y = (unsigned)f2bf(v0.z) | ((unsigned)f2bf(v0.w) << 16);
    o.z = (unsigned)f2bf(v1.x) | ((unsigned)f2bf(v1.y) << 16);
    o.w = (unsigned)f2bf(v1.z) | ((unsigned)f2bf(v1.w) << 16);
    reinterpret_cast<uint4*>(dst)[i] = o;
}

// ---------------------------------------------------------------------------
// All 4 weight transposes merged: fp32 [1024][C] -> bf16 [C][1024].
// ---------------------------------------------------------------------------
__global__ __launch_bounds__(256) void prep_weights(const float* __restrict__ Wq,
                                                    const float* __restrict__ Wk,
                                                    const float* __restrict__ Wv,
                                                    const float* __restrict__ Wp,
                                                    ushort* __restrict__ Wqkvt,
                                                    ushort* __restrict__ Wpt) {
    __shared__ float tile[32][33];
    const int x = blockIdx.x;
    const float* src; ushort* dst; int C, cx;
    if (x < 16)      { src = Wq; dst = Wqkvt;              C = 512;  cx = x; }
    else if (x < 20) { src = Wk; dst = Wqkvt + 512 * 1024; C = 128;  cx = x - 16; }
    else if (x < 28) { src = Wv; dst = Wqkvt + 640 * 1024; C = 256;  cx = x - 20; }
    else             { src = Wp; dst = Wpt;                C = 1024; cx = x - 28; }
    const int tx = threadIdx.x & 31, ty = threadIdx.x >> 5;
    const int r0 = blockIdx.y * 32, c0 = cx * 32;
#pragma unroll
    for (int i = 0; i < 32; i += 8)
        tile[ty + i][tx] = src[(size_t)(r0 + ty + i) * C + c0 + tx];
    __syncthreads();
#pragma unroll
    for (int i = 0; i < 32; i += 8)
        dst[(size_t)(c0 + ty + i) * 1024 + r0 + tx] = f2bf(tile[tx][ty + i]);
}

// ---------------------------------------------------------------------------
// bf16 strided transpose (for V): dst[z][c][r] = src[z*zoff + r*ld + c]
// ---------------------------------------------------------------------------
__global__ __launch_bounds__(256) void transpose_bf16_str(const ushort* __restrict__ src,
                                                          int src_ld, size_t src_zoff,
                                                          ushort* __restrict__ dst,
                                                          int R, int C, size_t dst_zoff) {
    __shared__ ushort tile[32][33];
    const int tx = threadIdx.x & 31, ty = threadIdx.x >> 5;
    const int r0 = blockIdx.y * 32, c0 = blockIdx.x * 32;
    const ushort* s = src + (size_t)blockIdx.z * src_zoff;
    ushort* d = dst + (size_t)blockIdx.z * dst_zoff;
#pragma unroll
    for (int i = 0; i < 32; i += 8)
        tile[ty + i][tx] = s[(size_t)(r0 + ty + i) * src_ld + c0 + tx];
    __syncthreads();
#pragma unroll
    for (int i = 0; i < 32; i += 8)
        d[(size_t)(c0 + ty + i) * R + r0 + tx] = tile[tx][ty + i];
}

// ---------------------------------------------------------------------------
// bf16 MFMA GEMM, m97-style global_load_lds staging. C = A[M,K] @ Bt[N,K]^T.
// Tile 64x128, BK=32, 4 waves (2x2), wave tile 32x64 = 2x4 frags of 16x16x32.
// Linear LDS [rows][32] (gload_lds requires contiguous lane-order dest).
// Grid (N/128, M/64) = 448/512 blocks -> 2 blocks/CU for latency overlap.
// ---------------------------------------------------------------------------
template <bool OUT_BF16>
__global__ __launch_bounds__(256) void gemm_bf16(const ushort* __restrict__ A,
                                                 const ushort* __restrict__ Bt,
                                                 const float* __restrict__ bias,
                                                 void* __restrict__ Cout,
                                                 int M, int N, int K) {
    __shared__ __align__(16) ushort As[64 * 32];
    __shared__ __align__(16) ushort Bs[128 * 32];

    const int tid = threadIdx.x;
    const int w = tid >> 6, l = tid & 63;
    const int bm = blockIdx.y * 64, bn = blockIdx.x * 128;
    const int wr = (w >> 1) * 32, wc = (w & 1) * 64;
    const int lr = l & 15, lk = (l >> 4) * 8;
    const int crow = l >> 2, ck8 = (l & 3) * 8;   // staging lane mapping

    // wave w stages A chunk w (16 rows) and B chunks {w, w+4}
    const ushort* Ag0 = A + (size_t)(bm + w * 16 + crow) * K + ck8;
    const ushort* Bg0 = Bt + (size_t)(bn + w * 16 + crow) * K + ck8;
    const ushort* Bg1 = Bt + (size_t)(bn + (w + 4) * 16 + crow) * K + ck8;
    ushort* Al0 = &As[w * 16 * 32];
    ushort* Bl0 = &Bs[w * 16 * 32];
    ushort* Bl1 = &Bs[(w + 4) * 16 * 32];

    f32x4 acc[2][4];
#pragma unroll
    for (int m = 0; m < 2; ++m)
#pragma unroll
        for (int n = 0; n < 4; ++n) acc[m][n] = (f32x4){0.f, 0.f, 0.f, 0.f};

    for (int k0 = 0; k0 < K; k0 += 32) {
        __syncthreads();   // prior iteration's LDS reads complete
        gl_lds16(Ag0 + k0, Al0);
        gl_lds16(Bg0 + k0, Bl0);
        gl_lds16(Bg1 + k0, Bl1);
        __syncthreads();   // compiler drains vmcnt before barrier -> tiles ready

        bf16x8 af[2], bfr[4];
#pragma unroll
        for (int m = 0; m < 2; ++m)
            af[m] = *reinterpret_cast<const bf16x8*>(&As[(wr + m * 16 + lr) * 32 + lk]);
#pragma unroll
        for (int n = 0; n < 4; ++n)
            bfr[n] = *reinterpret_cast<const bf16x8*>(&Bs[(wc + n * 16 + lr) * 32 + lk]);
#pragma unroll
        for (int m = 0; m < 2; ++m)
#pragma unroll
            for (int n = 0; n < 4; ++n)
                acc[m][n] = mfma16(af[m], bfr[n], acc[m][n]);
    }

    const int orow = bm + wr + (l >> 4) * 4;
    const int ocol0 = bn + wc + lr;
#pragma unroll
    for (int m = 0; m < 2; ++m)
#pragma unroll
        for (int n = 0; n < 4; ++n) {
            const int col = ocol0 + n * 16;
            const float bv = OUT_BF16 ? 0.0f : bias[col];
#pragma unroll
            for (int r = 0; r < 4; ++r) {
                const size_t idx = (size_t)(orow + m * 16 + r) * N + col;
                if constexpr (OUT_BF16)
                    reinterpret_cast<ushort*>(Cout)[idx] = f2bf(acc[m][n][r]);
                else
                    reinterpret_cast<float*>(Cout)[idx] = acc[m][n][r] + bv;
            }
        }
}

// ---------------------------------------------------------------------------
// Flash attention v7: uniform key-split, two sequential phases.
// Block = (tp, g, b), 512 threads, 8 waves: head hd = w&3 (h = g+4*hd),
// key-half grp = w>>2 (subtile grp of each staged 64-key tile).
// Phase 0: q-tile 63-tp (stages ceil((64-tp)/2)); phase 1: q-tile tp
// (stages ceil((tp+1)/2)). Total stages ~33 for EVERY block; every wave
// computes ~33 subtiles -> uniform globally AND within the block (2 active
// waves/SIMD throughout). Staging: R7-proven 1-barrier double-buffer,
// roles tid<256 K / tid>=256 V (permuted slots). Cross-group (o, l) combine
// per phase via barriered LDS scratch (reuses Vs) + lsred.
// ---------------------------------------------------------------------------
#define LDK 40
#define LDV 72

__global__ __launch_bounds__(512) void attn_mfma7(const ushort* __restrict__ qkv,
                                                  const ushort* __restrict__ vT,
                                                  ushort* __restrict__ ctx) {
    __shared__ __align__(16) ushort Ks[2][64 * LDK];
    __shared__ __align__(16) ushort Vs[2][64 * LDV];
    __shared__ float lsred[4][32];

    const int tid = threadIdx.x;
    const int w = tid >> 6, l = tid & 63;
    const int lq = l & 31;
    const int hi = l >> 5;
    const int tp = blockIdx.x, g = blockIdx.y, b = blockIdx.z;
    const int hd = w & 3, grp = w >> 2;
    const int h = g + 4 * hd;

    const float slope = exp2f(-0.5f * (float)(h + 1));
    const float k1 = 0.17677669529663687f * 1.4426950408889634f;  // scale*log2e
    const float k2 = slope * k1;
    const int Wint = (int)(275.0f / slope);

    // staging role split: tid<256 -> K, tid>=256 -> V
    const int st = tid & 255;
    const int sd = st >> 2;
    const int c4 = st & 3;
    const int sc8 = c4 * 8;
    const int voff = (c4 & 1) * 4 + (c4 >> 1) * 16;  // permuted V slot (ushorts)
    const ushort* kgp = qkv + (size_t)b * T_SEQ * QKV_LD + KOFF + g * 32 + (size_t)sd * QKV_LD + sc8;
    const ushort* vgp = vT + ((size_t)b * 256 + g * 64 + sd) * T_SEQ;

    float* red = reinterpret_cast<float*>(&Vs[0][0]);  // 16KB scratch (fits in Vs)

    int cur = 0;
    for (int ph = 0; ph < 2; ++ph) {
        const int t = ph ? tp : (63 - tp);
        const int i0 = t * 32;
        const int nkeys = i0 + 32;
        const int jtmax = (nkeys + 63) & ~63;

        // Q fragments for this phase's tile
        const ushort* qrow = qkv + ((size_t)(b * T_SEQ + i0 + lq)) * QKV_LD + h * 32 + hi * 8;
        const bf16x8 qa = *reinterpret_cast<const bf16x8*>(qrow);
        const bf16x8 qb = *reinterpret_cast<const bf16x8*>(qrow + 16);

        f32x16 o0, o1;
#pragma unroll
        for (int r = 0; r < 16; ++r) { o0[r] = 0.0f; o1[r] = 0.0f; }
        float ls = 0.0f;

        // phase prologue loads
        uint4 kreg, vr0, vr1;
        if (tid < 256) {
            kreg = *reinterpret_cast<const uint4*>(kgp);
        } else {
            vr0 = *reinterpret_cast<const uint4*>(vgp + sc8);
            vr1 = *reinterpret_cast<const uint4*>(vgp + 32 + sc8);
        }

        for (int jt = 0; jt < jtmax; jt += 64) {
            // stage buf[cur]
            if (tid < 256) {
                *reinterpret_cast<uint4*>(&Ks[cur][sd * LDK + sc8]) = kreg;
            } else {
                uint2 lo0 = make_uint2(vr0.x, vr0.y), hi0v = make_uint2(vr0.z, vr0.w);
                uint2 lo1 = make_uint2(vr1.x, vr1.y), hi1v = make_uint2(vr1.z, vr1.w);
                *reinterpret_cast<uint2*>(&Vs[cur][sd * LDV + voff]) = lo0;
                *reinterpret_cast<uint2*>(&Vs[cur][sd * LDV + voff + 8]) = hi0v;
                *reinterpret_cast<uint2*>(&Vs[cur][sd * LDV + 32 + voff]) = lo1;
                *reinterpret_cast<uint2*>(&Vs[cur][sd * LDV + 32 + voff + 8]) = hi1v;
            }
            // issue next-tile loads
            const int jn = jt + 64;
            if (jn < jtmax) {
                if (tid < 256) {
                    kreg = *reinterpret_cast<const uint4*>(kgp + (size_t)jn * QKV_LD);
                } else {
                    vr0 = *reinterpret_cast<const uint4*>(vgp + jn + sc8);
                    vr1 = *reinterpret_cast<const uint4*>(vgp + jn + 32 + sc8);
                }
            }
            __syncthreads();   // buf[cur] ready

            const int jts = jt + 32 * grp;   // this wave's key subtile
            if (jts < nkeys && jts + 31 >= i0 - Wint) {
                const bf16x8 ka = *reinterpret_cast<const bf16x8*>(&Ks[cur][(32 * grp + lq) * LDK + hi * 8]);
                const bf16x8 kb2 = *reinterpret_cast<const bf16x8*>(&Ks[cur][(32 * grp + lq) * LDK + 16 + hi * 8]);
                f32x16 p;
#pragma unroll
                for (int r = 0; r < 16; ++r) p[r] = 0.0f;
                __builtin_amdgcn_s_setprio(1);
                p = mfma32(ka, qa, p);
                p = mfma32(kb2, qb, p);
                __builtin_amdgcn_s_setprio(0);

                const int dlt = jts + 4 * hi - i0 - lq;
                const float base2 = k2 * (float)dlt;
                float pe[16];
                if (jts + 31 > i0) {   // diag subtile: masked path (uniform branch)
#pragma unroll
                    for (int r = 0; r < 16; ++r) {
                        const int off = (r & 3) + 8 * (r >> 2);
                        const float arg = fmaf(p[r], k1, fmaf((float)off, k2, base2));
                        float e = exp2f(arg);
                        if (dlt + off > 0) e = 0.0f;
                        ls += e;
                        pe[r] = e;
                    }
                } else {               // interior: no mask
#pragma unroll
                    for (int r = 0; r < 16; ++r) {
                        const int off = (r & 3) + 8 * (r >> 2);
                        const float arg = fmaf(p[r], k1, fmaf((float)off, k2, base2));
                        const float e = exp2f(arg);
                        ls += e;
                        pe[r] = e;
                    }
                }
                union { unsigned u[4]; bf16x8 v; } A1, A2;
#pragma unroll
                for (int j2 = 0; j2 < 4; ++j2) A1.u[j2] = pack2bf(pe[2 * j2], pe[2 * j2 + 1]);
#pragma unroll
                for (int j2 = 0; j2 < 4; ++j2) A2.u[j2] = pack2bf(pe[8 + 2 * j2], pe[9 + 2 * j2]);

                const int vr0i = lq * LDV + 32 * grp;
                const int vr1i = (32 + lq) * LDV + 32 * grp;
                const bf16x8 v00 = *reinterpret_cast<const bf16x8*>(&Vs[cur][vr0i + hi * 8]);
                const bf16x8 v01 = *reinterpret_cast<const bf16x8*>(&Vs[cur][vr0i + 16 + hi * 8]);
                const bf16x8 v10 = *reinterpret_cast<const bf16x8*>(&Vs[cur][vr1i + hi * 8]);
                const bf16x8 v11 = *reinterpret_cast<const bf16x8*>(&Vs[cur][vr1i + 16 + hi * 8]);
                __builtin_amdgcn_s_setprio(1);
                o0 = mfma32(A1.v, v00, o0);
                o0 = mfma32(A2.v, v01, o0);
                o1 = mfma32(A1.v, v10, o1);
                o1 = mfma32(A2.v, v11, o1);
                __builtin_amdgcn_s_setprio(0);
            }
            cur ^= 1;
        }

        // ---- cross-group combine (grp0 -> grp1 via LDS) ----
        const float ls2 = ls + __shfl_xor(ls, 32);   // in-wave: full subtotal for q=lq
        __syncthreads();   // all loop reads of Vs done -> safe to reuse as scratch
        if (grp == 0) {
#pragma unroll
            for (int r = 0; r < 16; ++r) red[hd * 1024 + l * 16 + r] = o0[r];
            if (hi == 0) lsred[hd][lq] = ls2;
        }
        __syncthreads();
        float inv = 0.0f;
        if (grp == 1) {
#pragma unroll
            for (int r = 0; r < 16; ++r) o0[r] += red[hd * 1024 + l * 16 + r];
            inv = 1.0f / (ls2 + lsred[hd][lq]);
        }
        __syncthreads();
        if (grp == 0) {
#pragma unroll
            for (int r = 0; r < 16; ++r) red[hd * 1024 + l * 16 + r] = o1[r];
        }
        __syncthreads();
        if (grp == 1) {
#pragma unroll
            for (int r = 0; r < 16; ++r) o1[r] += red[hd * 1024 + l * 16 + r];
#pragma unroll
            for (int r = 0; r < 16; ++r) {
                const int qr = (r & 3) + 8 * (r >> 2) + 4 * hi;
                const float invq = __shfl(inv, qr);
                const size_t row = (size_t)(b * T_SEQ + i0 + qr);
                ctx[row * 1024 + h * 64 + lq] = f2bf(o0[r] * invq);
                ctx[row * 1024 + h * 64 + 32 + lq] = f2bf(o1[r] * invq);
            }
        }
        __syncthreads();   // scratch reads done before next phase stages into Vs
    }
}

// ---------------------------------------------------------------------------
extern "C" void kernel_launch(void* const* d_in, const int* in_sizes, int n_in,
                              void* d_out, int out_size, void* d_ws, size_t ws_size,
                              hipStream_t stream) {
    const float* x  = (const float*)d_in[0];
    const float* Wq = (const float*)d_in[1];
    const float* Wk = (const float*)d_in[2];
    const float* Wv = (const float*)d_in[3];
    const float* Wp = (const float*)d_in[4];
    const float* bp = (const float*)d_in[5];

    const int M = B_SZ * T_SEQ;  // 4096

    ushort* ws    = (ushort*)d_ws;
    ushort* xb    = ws;                   // 4096x1024
    ushort* Wqkvt = xb + 4194304;         // 896x1024 (rows: Wq^T | Wk^T | Wv^T)
    ushort* Wpt   = Wqkvt + 917504;       // 1024x1024
    ushort* qkv   = Wpt + 1048576;        // 4096x896
    ushort* vTb   = qkv + 3670016;        // 2x256x2048
    ushort* cbuf  = vTb + 1048576;        // 4096x1024

    convert_bf16<<<2048, 256, 0, stream>>>(x, xb);
    prep_weights<<<dim3(60, 32), 256, 0, stream>>>(Wq, Wk, Wv, Wp, Wqkvt, Wpt);

    gemm_bf16<true><<<dim3(7, 64), 256, 0, stream>>>(xb, Wqkvt, nullptr, qkv, M, 896, 1024);

    transpose_bf16_str<<<dim3(8, 64, 2), 256, 0, stream>>>(
        qkv + VOFF, QKV_LD, (size_t)T_SEQ * QKV_LD, vTb, T_SEQ, 256, (size_t)256 * T_SEQ);

    attn_mfma7<<<dim3(32, 4, B_SZ), 512, 0, stream>>>(qkv, vTb, cbuf);

    gemm_bf16<false><<<dim3(8, 64), 256, 0, stream>>>(cbuf, Wpt, bp, (float*)d_out, M, 1024, 1024);
}